// Round 1
// baseline (1736.461 us; speedup 1.0000x reference)
//
#include <hip/hip_runtime.h>
#include <hip/hip_bf16.h>

// Problem constants (MultiTaskFEGIN): N=100000, E=1200000, F=32, H=64, L=3,
// G=256, C=200000, NC=10, D=L*H=192.

#define GG 256
#define NCC 10
#define DD 192

// ---------------------------------------------------------------------------
// Edge-parallel scatter-add: agg[dst[e]][k] += hsrc[src[e]][k]
// ---------------------------------------------------------------------------
template<int LOGD>
__global__ void scatter_add_k(const float* __restrict__ hsrc, int in_stride,
                              const int* __restrict__ src, const int* __restrict__ dst,
                              float* __restrict__ agg, int E_) {
    constexpr int DIM = 1 << LOGD;
    int idx = blockIdx.x * blockDim.x + threadIdx.x;
    int e = idx >> LOGD;
    int k = idx & (DIM - 1);
    if (e >= E_) return;
    int s = src[e];
    int d = dst[e];
    atomicAdd(agg + ((long long)d << LOGD) + k,
              hsrc[(long long)s * in_stride + k]);
}

// ---------------------------------------------------------------------------
// Fused per-node GIN MLP: hin=(1+eps)*h+agg; t1=relu(hin@W1+b1);
// t2=relu(t1@W2+b2); out = bn(t2). 8 nodes x 64 dims per 512-thread block.
// ---------------------------------------------------------------------------
template<int K>
__global__ void gin_node_mlp(const float* __restrict__ hin, int in_stride,
                             const float* __restrict__ agg,
                             const float* __restrict__ W1, const float* __restrict__ b1,
                             const float* __restrict__ W2, const float* __restrict__ b2,
                             const float* __restrict__ gamma, const float* __restrict__ beta,
                             const float* __restrict__ mean, const float* __restrict__ var,
                             const float* __restrict__ eps_p,
                             float* __restrict__ out, int out_stride, int N_) {
    constexpr int NT = 8;
    __shared__ float s_hin[NT][K];
    __shared__ float s_t1[NT][64];
    __shared__ float s_W1[K * 64];
    __shared__ float s_W2[64 * 64];

    const int t  = threadIdx.x;      // 0..511
    const int d  = t & 63;
    const int ni = t >> 6;           // 0..7
    const int node = blockIdx.x * NT + ni;

    for (int i = t; i < K * 64; i += NT * 64) s_W1[i] = W1[i];
    for (int i = t; i < 64 * 64; i += NT * 64) s_W2[i] = W2[i];

    const float eps1 = 1.0f + eps_p[0];
    if (node < N_ && d < K) {
        s_hin[ni][d] = eps1 * hin[(long long)node * in_stride + d]
                     + agg[(long long)node * K + d];
    }
    __syncthreads();

    float acc = b1[d];
    #pragma unroll
    for (int k = 0; k < K; ++k) acc += s_hin[ni][k] * s_W1[k * 64 + d];
    s_t1[ni][d] = fmaxf(acc, 0.0f);
    __syncthreads();

    float acc2 = b2[d];
    #pragma unroll
    for (int k = 0; k < 64; ++k) acc2 += s_t1[ni][k] * s_W2[k * 64 + d];
    acc2 = fmaxf(acc2, 0.0f);
    float o = gamma[d] * (acc2 - mean[d]) * rsqrtf(var[d] + 1e-5f) + beta[d];
    if (node < N_) out[(long long)node * out_stride + d] = o;
}

// ---------------------------------------------------------------------------
// Mean-pool (batch sorted): per-block run-length accumulation over 256-node
// chunks, atomic flush on graph transition.
// ---------------------------------------------------------------------------
__global__ void pool_kernel(const float* __restrict__ node_emb, const int* __restrict__ batch,
                            float* __restrict__ gsum, float* __restrict__ gcnt, int N_) {
    const int CHUNK = 256;
    __shared__ int sb[CHUNK];
    const int n0 = blockIdx.x * CHUNK;
    const int t  = threadIdx.x;                 // block = 256
    const int cnt_local = min(n0 + CHUNK, N_) - n0;
    if (t < cnt_local) sb[t] = batch[n0 + t];
    __syncthreads();
    if (cnt_local <= 0) return;

    if (t < DD) {
        float acc = 0.0f;
        int curg = sb[0];
        for (int n = 0; n < cnt_local; ++n) {
            int g = sb[n];
            if (g != curg) {
                atomicAdd(&gsum[curg * DD + t], acc);
                acc = 0.0f; curg = g;
            }
            acc += node_emb[(long long)(n0 + n) * DD + t];
        }
        atomicAdd(&gsum[curg * DD + t], acc);
    } else if (t == DD) {
        int c = 1, curg = sb[0];
        for (int n = 1; n < cnt_local; ++n) {
            if (sb[n] != curg) {
                atomicAdd(&gcnt[curg], (float)c);
                c = 0; curg = sb[n];
            }
            ++c;
        }
        atomicAdd(&gcnt[curg], (float)c);
    }
}

// ---------------------------------------------------------------------------
// Classification head: one block (256 threads) per graph.
// 192 -> 128 -> 64 -> 64 -> 10, log_softmax, argmax -> comp_idx
// ---------------------------------------------------------------------------
__global__ void head_kernel(const float* __restrict__ gsum, const float* __restrict__ gcnt,
                            const float* __restrict__ W1, const float* __restrict__ b1,
                            const float* __restrict__ W2, const float* __restrict__ b2,
                            const float* __restrict__ W3, const float* __restrict__ b3,
                            const float* __restrict__ W4, const float* __restrict__ b4,
                            float* __restrict__ class_out, int* __restrict__ comp_idx) {
    const int g = blockIdx.x;
    const int t = threadIdx.x;
    __shared__ float ge[DD], h1[128], h2[64], h3[64], logits[NCC];

    const float c = fmaxf(gcnt[g], 1.0f);
    if (t < DD) ge[t] = gsum[g * DD + t] / c;
    __syncthreads();

    if (t < 128) {
        float a = b1[t];
        #pragma unroll 4
        for (int k = 0; k < DD; ++k) a += ge[k] * W1[k * 128 + t];
        h1[t] = fmaxf(a, 0.0f);
    }
    __syncthreads();
    if (t < 64) {
        float a = b2[t];
        #pragma unroll 4
        for (int k = 0; k < 128; ++k) a += h1[k] * W2[k * 64 + t];
        h2[t] = fmaxf(a, 0.0f);
    }
    __syncthreads();
    if (t < 64) {
        float a = b3[t];
        #pragma unroll 4
        for (int k = 0; k < 64; ++k) a += h2[k] * W3[k * 64 + t];
        h3[t] = fmaxf(a, 0.0f);
    }
    __syncthreads();
    if (t < NCC) {
        float a = b4[t];
        #pragma unroll
        for (int k = 0; k < 64; ++k) a += h3[k] * W4[k * NCC + t];
        logits[t] = a;
    }
    __syncthreads();
    if (t == 0) {
        float mx = logits[0]; int am = 0;
        for (int j = 1; j < NCC; ++j) if (logits[j] > mx) { mx = logits[j]; am = j; }
        float se = 0.0f;
        for (int j = 0; j < NCC; ++j) se += expf(logits[j] - mx);
        float lse = logf(se);
        for (int j = 0; j < NCC; ++j) class_out[g * NCC + j] = logits[j] - mx - lse;
        comp_idx[g] = am;
    }
}

// ---------------------------------------------------------------------------
// Edge-prediction MLP: ef=[comp_emb[ci] | node_emb[cand]] (384) -> 128 -> 64
// -> sigmoid scalar. 32 candidates / 256-thread block; ef/h1/h2 in LDS,
// 4x4 register tile against coalesced global W reads (W L2-resident).
// ---------------------------------------------------------------------------
__global__ void edge_kernel(const int* __restrict__ cand_node, const int* __restrict__ batch,
                            const int* __restrict__ comp_idx, const float* __restrict__ comp_emb,
                            const float* __restrict__ node_emb,
                            const float* __restrict__ W1, const float* __restrict__ b1,
                            const float* __restrict__ W2, const float* __restrict__ b2,
                            const float* __restrict__ W3, const float* __restrict__ b3,
                            float* __restrict__ scores, int C_) {
    constexpr int TC = 32;
    __shared__ float ef[TC][384];
    __shared__ float h1l[TC][128];
    __shared__ float h2l[TC][64];
    __shared__ int s_node[TC];
    __shared__ int s_ci[TC];

    const int t  = threadIdx.x;   // 256
    const int c0 = blockIdx.x * TC;

    if (t < TC) {
        int c = c0 + t;
        int node = (c < C_) ? cand_node[c] : cand_node[0];
        s_node[t] = node;
        s_ci[t] = comp_idx[batch[node]];
    }
    __syncthreads();

    for (int i = t; i < TC * 384; i += 256) {
        int c = i / 384;
        int k = i - c * 384;
        float v = (k < DD) ? comp_emb[s_ci[c] * DD + k]
                           : node_emb[(long long)s_node[c] * DD + (k - DD)];
        ef[c][k] = v;
    }
    __syncthreads();

    // h1 = relu(ef @ W1 + b1): [32 x 384] @ [384 x 128]
    {
        const int dg = (t & 31) << 2;   // 0..124
        const int cg = (t >> 5) << 2;   // 0..28
        float acc[4][4];
        #pragma unroll
        for (int ci = 0; ci < 4; ++ci)
            #pragma unroll
            for (int di = 0; di < 4; ++di) acc[ci][di] = b1[dg + di];
        for (int k = 0; k < 384; k += 4) {
            float4 w0 = *(const float4*)(W1 + (k + 0) * 128 + dg);
            float4 w1 = *(const float4*)(W1 + (k + 1) * 128 + dg);
            float4 w2 = *(const float4*)(W1 + (k + 2) * 128 + dg);
            float4 w3 = *(const float4*)(W1 + (k + 3) * 128 + dg);
            #pragma unroll
            for (int ci = 0; ci < 4; ++ci) {
                float4 e = *(const float4*)(&ef[cg + ci][k]);
                acc[ci][0] += e.x * w0.x + e.y * w1.x + e.z * w2.x + e.w * w3.x;
                acc[ci][1] += e.x * w0.y + e.y * w1.y + e.z * w2.y + e.w * w3.y;
                acc[ci][2] += e.x * w0.z + e.y * w1.z + e.z * w2.z + e.w * w3.z;
                acc[ci][3] += e.x * w0.w + e.y * w1.w + e.z * w2.w + e.w * w3.w;
            }
        }
        #pragma unroll
        for (int ci = 0; ci < 4; ++ci)
            #pragma unroll
            for (int di = 0; di < 4; ++di)
                h1l[cg + ci][dg + di] = fmaxf(acc[ci][di], 0.0f);
    }
    __syncthreads();

    // h2 = relu(h1 @ W2 + b2): [32 x 128] @ [128 x 64]
    {
        const int dg = (t & 15) << 2;   // 0..60
        const int cg = (t >> 4) << 1;   // 0..30
        float acc[2][4];
        #pragma unroll
        for (int ci = 0; ci < 2; ++ci)
            #pragma unroll
            for (int di = 0; di < 4; ++di) acc[ci][di] = b2[dg + di];
        for (int k = 0; k < 128; k += 4) {
            float4 w0 = *(const float4*)(W2 + (k + 0) * 64 + dg);
            float4 w1 = *(const float4*)(W2 + (k + 1) * 64 + dg);
            float4 w2 = *(const float4*)(W2 + (k + 2) * 64 + dg);
            float4 w3 = *(const float4*)(W2 + (k + 3) * 64 + dg);
            #pragma unroll
            for (int ci = 0; ci < 2; ++ci) {
                float4 e = *(const float4*)(&h1l[cg + ci][k]);
                acc[ci][0] += e.x * w0.x + e.y * w1.x + e.z * w2.x + e.w * w3.x;
                acc[ci][1] += e.x * w0.y + e.y * w1.y + e.z * w2.y + e.w * w3.y;
                acc[ci][2] += e.x * w0.z + e.y * w1.z + e.z * w2.z + e.w * w3.z;
                acc[ci][3] += e.x * w0.w + e.y * w1.w + e.z * w2.w + e.w * w3.w;
            }
        }
        #pragma unroll
        for (int ci = 0; ci < 2; ++ci)
            #pragma unroll
            for (int di = 0; di < 4; ++di)
                h2l[cg + ci][dg + di] = fmaxf(acc[ci][di], 0.0f);
    }
    __syncthreads();

    if (t < TC) {
        int c = c0 + t;
        if (c < C_) {
            float a = b3[0];
            #pragma unroll 4
            for (int k = 0; k < 64; ++k) a += h2l[t][k] * W3[k];
            scores[c] = 1.0f / (1.0f + expf(-a));
        }
    }
}

// ---------------------------------------------------------------------------
extern "C" void kernel_launch(void* const* d_in, const int* in_sizes, int n_in,
                              void* d_out, int out_size, void* d_ws, size_t ws_size,
                              hipStream_t stream) {
    const float* x        = (const float*)d_in[0];
    const int*   ei       = (const int*)d_in[1];
    const int*   batch    = (const int*)d_in[2];
    const int*   cand     = (const int*)d_in[3];
    const float* c1_W1    = (const float*)d_in[4];
    const float* c1_b1    = (const float*)d_in[5];
    const float* c1_W2    = (const float*)d_in[6];
    const float* c1_b2    = (const float*)d_in[7];
    const float* c1_g     = (const float*)d_in[8];
    const float* c1_be    = (const float*)d_in[9];
    const float* c1_m     = (const float*)d_in[10];
    const float* c1_v     = (const float*)d_in[11];
    const float* c1_eps   = (const float*)d_in[12];
    const float* cs_W1    = (const float*)d_in[13];
    const float* cs_b1    = (const float*)d_in[14];
    const float* cs_W2    = (const float*)d_in[15];
    const float* cs_b2    = (const float*)d_in[16];
    const float* cs_g     = (const float*)d_in[17];
    const float* cs_be    = (const float*)d_in[18];
    const float* cs_m     = (const float*)d_in[19];
    const float* cs_v     = (const float*)d_in[20];
    const float* cs_eps   = (const float*)d_in[21];
    const float* nc_W1    = (const float*)d_in[22];
    const float* nc_b1    = (const float*)d_in[23];
    const float* nc_W2    = (const float*)d_in[24];
    const float* nc_b2    = (const float*)d_in[25];
    const float* nc_W3    = (const float*)d_in[26];
    const float* nc_b3    = (const float*)d_in[27];
    const float* nc_W4    = (const float*)d_in[28];
    const float* nc_b4    = (const float*)d_in[29];
    const float* comp_emb = (const float*)d_in[30];
    const float* ep_W1    = (const float*)d_in[31];
    const float* ep_b1    = (const float*)d_in[32];
    const float* ep_W2    = (const float*)d_in[33];
    const float* ep_b2    = (const float*)d_in[34];
    const float* ep_W3    = (const float*)d_in[35];
    const float* ep_b3    = (const float*)d_in[36];

    const int N_ = in_sizes[0] / 32;
    const int E_ = in_sizes[1] / 2;
    const int C_ = in_sizes[3];
    const int* src = ei;
    const int* dst = ei + E_;

    char* ws = (char*)d_ws;
    float* agg      = (float*)ws;                                   // N*64 f32
    float* node_emb = (float*)(ws + (size_t)N_ * 64 * 4);           // N*192 f32
    float* gsum     = (float*)(ws + (size_t)N_ * 64 * 4 + (size_t)N_ * 192 * 4);
    float* gcnt     = gsum + GG * DD;
    int*   comp_idx = (int*)(gcnt + GG);

    float* class_out = (float*)d_out;          // 256*10
    float* scores    = class_out + GG * NCC;   // 200000

    // ---- GIN layer 1 (K=32) ----
    hipMemsetAsync(agg, 0, (size_t)N_ * 32 * 4, stream);
    scatter_add_k<5><<<(E_ * 32 + 255) / 256, 256, 0, stream>>>(x, 32, src, dst, agg, E_);
    gin_node_mlp<32><<<(N_ + 7) / 8, 512, 0, stream>>>(
        x, 32, agg, c1_W1, c1_b1, c1_W2, c1_b2, c1_g, c1_be, c1_m, c1_v, c1_eps,
        node_emb + 0, DD, N_);

    // ---- GIN layer 2 (K=64) ----
    hipMemsetAsync(agg, 0, (size_t)N_ * 64 * 4, stream);
    scatter_add_k<6><<<(E_ * 64 + 255) / 256, 256, 0, stream>>>(node_emb + 0, DD, src, dst, agg, E_);
    gin_node_mlp<64><<<(N_ + 7) / 8, 512, 0, stream>>>(
        node_emb + 0, DD, agg,
        cs_W1 + 0 * 4096, cs_b1 + 0 * 64, cs_W2 + 0 * 4096, cs_b2 + 0 * 64,
        cs_g + 0 * 64, cs_be + 0 * 64, cs_m + 0 * 64, cs_v + 0 * 64, cs_eps + 0,
        node_emb + 64, DD, N_);

    // ---- GIN layer 3 (K=64) ----
    hipMemsetAsync(agg, 0, (size_t)N_ * 64 * 4, stream);
    scatter_add_k<6><<<(E_ * 64 + 255) / 256, 256, 0, stream>>>(node_emb + 64, DD, src, dst, agg, E_);
    gin_node_mlp<64><<<(N_ + 7) / 8, 512, 0, stream>>>(
        node_emb + 64, DD, agg,
        cs_W1 + 1 * 4096, cs_b1 + 1 * 64, cs_W2 + 1 * 4096, cs_b2 + 1 * 64,
        cs_g + 1 * 64, cs_be + 1 * 64, cs_m + 1 * 64, cs_v + 1 * 64, cs_eps + 1,
        node_emb + 128, DD, N_);

    // ---- mean pool + head ----
    hipMemsetAsync(gsum, 0, (size_t)(GG * DD + GG) * 4, stream);
    pool_kernel<<<(N_ + 255) / 256, 256, 0, stream>>>(node_emb, batch, gsum, gcnt, N_);
    head_kernel<<<GG, 256, 0, stream>>>(gsum, gcnt, nc_W1, nc_b1, nc_W2, nc_b2,
                                        nc_W3, nc_b3, nc_W4, nc_b4, class_out, comp_idx);

    // ---- edge prediction ----
    edge_kernel<<<(C_ + 31) / 32, 256, 0, stream>>>(
        cand, batch, comp_idx, comp_emb, node_emb,
        ep_W1, ep_b1, ep_W2, ep_b2, ep_W3, ep_b3, scores, C_);
}

// Round 2
// 1088.174 us; speedup vs baseline: 1.5958x; 1.5958x over previous
//
#include <hip/hip_runtime.h>
#include <hip/hip_bf16.h>

// Problem constants (MultiTaskFEGIN): N=100000, E=1200000, F=32, H=64, L=3,
// G=256, C=200000, NC=10, D=L*H=192.

#define GG 256
#define NCC 10
#define DD 192

typedef short bf16x8 __attribute__((ext_vector_type(8)));
typedef float f32x4  __attribute__((ext_vector_type(4)));

__device__ inline unsigned short f2bf_u(float x) {
    __hip_bfloat16 h = __float2bfloat16(x);
    return *reinterpret_cast<unsigned short*>(&h);
}

// ---------------------------------------------------------------------------
// Edge-parallel scatter-add: agg[dst[e]][k] += hsrc[src[e]][k]
// ---------------------------------------------------------------------------
template<int LOGD>
__global__ void scatter_add_k(const float* __restrict__ hsrc, int in_stride,
                              const int* __restrict__ src, const int* __restrict__ dst,
                              float* __restrict__ agg, int E_) {
    constexpr int DIM = 1 << LOGD;
    int idx = blockIdx.x * blockDim.x + threadIdx.x;
    int e = idx >> LOGD;
    int k = idx & (DIM - 1);
    if (e >= E_) return;
    int s = src[e];
    int d = dst[e];
    atomicAdd(agg + ((long long)d << LOGD) + k,
              hsrc[(long long)s * in_stride + k]);
}

// ---------------------------------------------------------------------------
// Fused per-node GIN MLP: hin=(1+eps)*h+agg; t1=relu(hin@W1+b1);
// t2=relu(t1@W2+b2); out = bn(t2). 8 nodes x 64 dims per 512-thread block.
// ---------------------------------------------------------------------------
template<int K>
__global__ void gin_node_mlp(const float* __restrict__ hin, int in_stride,
                             const float* __restrict__ agg,
                             const float* __restrict__ W1, const float* __restrict__ b1,
                             const float* __restrict__ W2, const float* __restrict__ b2,
                             const float* __restrict__ gamma, const float* __restrict__ beta,
                             const float* __restrict__ mean, const float* __restrict__ var,
                             const float* __restrict__ eps_p,
                             float* __restrict__ out, int out_stride, int N_) {
    constexpr int NT = 8;
    __shared__ float s_hin[NT][K];
    __shared__ float s_t1[NT][64];
    __shared__ float s_W1[K * 64];
    __shared__ float s_W2[64 * 64];

    const int t  = threadIdx.x;      // 0..511
    const int d  = t & 63;
    const int ni = t >> 6;           // 0..7
    const int node = blockIdx.x * NT + ni;

    for (int i = t; i < K * 64; i += NT * 64) s_W1[i] = W1[i];
    for (int i = t; i < 64 * 64; i += NT * 64) s_W2[i] = W2[i];

    const float eps1 = 1.0f + eps_p[0];
    if (node < N_ && d < K) {
        s_hin[ni][d] = eps1 * hin[(long long)node * in_stride + d]
                     + agg[(long long)node * K + d];
    }
    __syncthreads();

    float acc = b1[d];
    #pragma unroll
    for (int k = 0; k < K; ++k) acc += s_hin[ni][k] * s_W1[k * 64 + d];
    s_t1[ni][d] = fmaxf(acc, 0.0f);
    __syncthreads();

    float acc2 = b2[d];
    #pragma unroll
    for (int k = 0; k < 64; ++k) acc2 += s_t1[ni][k] * s_W2[k * 64 + d];
    acc2 = fmaxf(acc2, 0.0f);
    float o = gamma[d] * (acc2 - mean[d]) * rsqrtf(var[d] + 1e-5f) + beta[d];
    if (node < N_) out[(long long)node * out_stride + d] = o;
}

// ---------------------------------------------------------------------------
// Mean-pool (batch sorted): per-block run-length accumulation over 256-node
// chunks, atomic flush on graph transition.
// ---------------------------------------------------------------------------
__global__ void pool_kernel(const float* __restrict__ node_emb, const int* __restrict__ batch,
                            float* __restrict__ gsum, float* __restrict__ gcnt, int N_) {
    const int CHUNK = 256;
    __shared__ int sb[CHUNK];
    const int n0 = blockIdx.x * CHUNK;
    const int t  = threadIdx.x;                 // block = 256
    const int cnt_local = min(n0 + CHUNK, N_) - n0;
    if (t < cnt_local) sb[t] = batch[n0 + t];
    __syncthreads();
    if (cnt_local <= 0) return;

    if (t < DD) {
        float acc = 0.0f;
        int curg = sb[0];
        for (int n = 0; n < cnt_local; ++n) {
            int g = sb[n];
            if (g != curg) {
                atomicAdd(&gsum[curg * DD + t], acc);
                acc = 0.0f; curg = g;
            }
            acc += node_emb[(long long)(n0 + n) * DD + t];
        }
        atomicAdd(&gsum[curg * DD + t], acc);
    } else if (t == DD) {
        int c = 1, curg = sb[0];
        for (int n = 1; n < cnt_local; ++n) {
            if (sb[n] != curg) {
                atomicAdd(&gcnt[curg], (float)c);
                c = 0; curg = sb[n];
            }
            ++c;
        }
        atomicAdd(&gcnt[curg], (float)c);
    }
}

// ---------------------------------------------------------------------------
// Classification head: one block (256 threads) per graph.
// ---------------------------------------------------------------------------
__global__ void head_kernel(const float* __restrict__ gsum, const float* __restrict__ gcnt,
                            const float* __restrict__ W1, const float* __restrict__ b1,
                            const float* __restrict__ W2, const float* __restrict__ b2,
                            const float* __restrict__ W3, const float* __restrict__ b3,
                            const float* __restrict__ W4, const float* __restrict__ b4,
                            float* __restrict__ class_out, int* __restrict__ comp_idx) {
    const int g = blockIdx.x;
    const int t = threadIdx.x;
    __shared__ float ge[DD], h1[128], h2[64], h3[64], logits[NCC];

    const float c = fmaxf(gcnt[g], 1.0f);
    if (t < DD) ge[t] = gsum[g * DD + t] / c;
    __syncthreads();

    if (t < 128) {
        float a = b1[t];
        #pragma unroll 4
        for (int k = 0; k < DD; ++k) a += ge[k] * W1[k * 128 + t];
        h1[t] = fmaxf(a, 0.0f);
    }
    __syncthreads();
    if (t < 64) {
        float a = b2[t];
        #pragma unroll 4
        for (int k = 0; k < 128; ++k) a += h1[k] * W2[k * 64 + t];
        h2[t] = fmaxf(a, 0.0f);
    }
    __syncthreads();
    if (t < 64) {
        float a = b3[t];
        #pragma unroll 4
        for (int k = 0; k < 64; ++k) a += h2[k] * W3[k * 64 + t];
        h3[t] = fmaxf(a, 0.0f);
    }
    __syncthreads();
    if (t < NCC) {
        float a = b4[t];
        #pragma unroll
        for (int k = 0; k < 64; ++k) a += h3[k] * W4[k * NCC + t];
        logits[t] = a;
    }
    __syncthreads();
    if (t == 0) {
        float mx = logits[0]; int am = 0;
        for (int j = 1; j < NCC; ++j) if (logits[j] > mx) { mx = logits[j]; am = j; }
        float se = 0.0f;
        for (int j = 0; j < NCC; ++j) se += expf(logits[j] - mx);
        float lse = logf(se);
        for (int j = 0; j < NCC; ++j) class_out[g * NCC + j] = logits[j] - mx - lse;
        comp_idx[g] = am;
    }
}

// ---------------------------------------------------------------------------
// prep_edge: pack ep_W1 (de half, rows 192..383) and ep_W2 into per-wave
// bf16 MFMA B-fragment order; compute pc[10][128] = comp_emb @ W1a + b1.
// B-frag layout (16x16x32): lane l holds B[k=(l>>4)*8+j][n=l&15], j=0..7.
// packed[frag*512 + lane*8 + j], frag = kstep*NT + nt.
// ---------------------------------------------------------------------------
__global__ void prep_edge(const float* __restrict__ W1, const float* __restrict__ b1,
                          const float* __restrict__ W2, const float* __restrict__ comp_emb,
                          unsigned short* __restrict__ W1b_p, unsigned short* __restrict__ W2_p,
                          float* __restrict__ pc) {
    int idx = blockIdx.x * 256 + threadIdx.x;
    const int S1 = 6 * 8 * 512;   // W1b frags: K=192 (6 ksteps) x N=128 (8 ntiles)
    const int S2 = 4 * 4 * 512;   // W2  frags: K=128 (4)        x N=64  (4)
    if (idx < S1) {
        int frag = idx >> 9;
        int lane = (idx >> 3) & 63;
        int j = idx & 7;
        int kstep = frag >> 3, nt = frag & 7;
        int k = kstep * 32 + ((lane >> 4) << 3) + j;
        int n = nt * 16 + (lane & 15);
        W1b_p[idx] = f2bf_u(W1[(192 + k) * 128 + n]);
    } else if (idx < S1 + S2) {
        int i2 = idx - S1;
        int frag = i2 >> 9;
        int lane = (i2 >> 3) & 63;
        int j = i2 & 7;
        int kstep = frag >> 2, nt = frag & 3;
        int k = kstep * 32 + ((lane >> 4) << 3) + j;
        int n = nt * 16 + (lane & 15);
        W2_p[i2] = f2bf_u(W2[k * 64 + n]);
    } else if (idx < S1 + S2 + NCC * 128) {
        int i3 = idx - (S1 + S2);
        int ci = i3 >> 7, col = i3 & 127;
        float a = b1[col];
        for (int k = 0; k < DD; ++k) a += comp_emb[ci * DD + k] * W1[k * 128 + col];
        pc[i3] = a;
    }
}

// ---------------------------------------------------------------------------
// edge_mfma: 64 candidates per 256-thread block (4 waves, 16 rows/wave).
// h1 = relu(de @ W1b + pc[ci]);  score = sigmoid(relu(h1 @ W2) . W3 + b3)
// de gathered fp32->bf16 into XOR-swizzled LDS; B frags from packed global.
// ---------------------------------------------------------------------------
__global__ __launch_bounds__(256) void edge_mfma(
    const int* __restrict__ cand, const int* __restrict__ batch,
    const int* __restrict__ comp_idx, const float* __restrict__ node_emb,
    const unsigned short* __restrict__ W1b_p, const unsigned short* __restrict__ W2_p,
    const float* __restrict__ pc, const float* __restrict__ W3,
    const float* __restrict__ b3, float* __restrict__ scores, int C_) {
    __shared__ char s_de[64 * 384];   // bf16 [64][192], swizzled by ^((row&7)<<4)
    __shared__ char s_h1[64 * 256];   // bf16 [64][128], swizzled
    __shared__ int s_node[64];
    __shared__ int s_ci[64];
    __shared__ float s_pc[NCC * 128];
    __shared__ float s_w3[64];

    const int t = threadIdx.x;
    const int lane = t & 63;
    const int w = t >> 6;             // wave 0..3
    const int c0 = blockIdx.x * 64;

    if (t < 64) {
        int c = c0 + t;
        int node = (c < C_) ? cand[c] : cand[0];
        s_node[t] = node;
        s_ci[t] = comp_idx[batch[node]];
        s_w3[t] = W3[t];
    }
    for (int i = t; i < NCC * 128; i += 256) s_pc[i] = pc[i];
    __syncthreads();

    // gather de rows -> LDS bf16 (convert in flight), swizzled
    for (int i = t; i < 64 * 48; i += 256) {
        int r = i / 48, c4 = i - r * 48;            // 48 float4-chunks per row
        float4 v = *(const float4*)(node_emb + (long long)s_node[r] * DD + c4 * 4);
        ushort4 u;
        u.x = f2bf_u(v.x); u.y = f2bf_u(v.y); u.z = f2bf_u(v.z); u.w = f2bf_u(v.w);
        int off = r * 384 + c4 * 8;
        *(ushort4*)(s_de + (off ^ ((r & 7) << 4))) = u;
    }
    __syncthreads();

    // ---- GEMM1: de[16x192] @ W1b[192x128] per wave ----
    f32x4 acc1[8];
    #pragma unroll
    for (int nt = 0; nt < 8; ++nt) acc1[nt] = (f32x4){0.f, 0.f, 0.f, 0.f};
    const int arow = w * 16 + (lane & 15);
    const int abase = arow * 384 + ((lane >> 4) << 4);
    #pragma unroll
    for (int ks = 0; ks < 6; ++ks) {
        bf16x8 a = *(const bf16x8*)(s_de + ((abase + ks * 64) ^ ((arow & 7) << 4)));
        #pragma unroll
        for (int nt = 0; nt < 8; ++nt) {
            bf16x8 b = *(const bf16x8*)(W1b_p + ((ks * 8 + nt) << 9) + (lane << 3));
            acc1[nt] = __builtin_amdgcn_mfma_f32_16x16x32_bf16(a, b, acc1[nt], 0, 0, 0);
        }
    }
    // epilogue 1: + pc[ci], relu, -> bf16 LDS h1 (swizzled)
    {
        const int rq = (lane >> 4) << 2;
        #pragma unroll
        for (int reg = 0; reg < 4; ++reg) {
            int row = w * 16 + rq + reg;
            int ci = s_ci[row];
            #pragma unroll
            for (int nt = 0; nt < 8; ++nt) {
                int col = nt * 16 + (lane & 15);
                float v = acc1[nt][reg] + s_pc[ci * 128 + col];
                v = fmaxf(v, 0.0f);
                int off = row * 256 + col * 2;
                *(unsigned short*)(s_h1 + (off ^ ((row & 7) << 4))) = f2bf_u(v);
            }
        }
    }
    __syncthreads();

    // ---- GEMM2: h1[16x128] @ W2[128x64] per wave ----
    f32x4 acc2[4];
    #pragma unroll
    for (int nt = 0; nt < 4; ++nt) acc2[nt] = (f32x4){0.f, 0.f, 0.f, 0.f};
    const int a2base = arow * 256 + ((lane >> 4) << 4);
    #pragma unroll
    for (int ks = 0; ks < 4; ++ks) {
        bf16x8 a = *(const bf16x8*)(s_h1 + ((a2base + ks * 64) ^ ((arow & 7) << 4)));
        #pragma unroll
        for (int nt = 0; nt < 4; ++nt) {
            bf16x8 b = *(const bf16x8*)(W2_p + ((ks * 4 + nt) << 9) + (lane << 3));
            acc2[nt] = __builtin_amdgcn_mfma_f32_16x16x32_bf16(a, b, acc2[nt], 0, 0, 0);
        }
    }
    // epilogue 2: relu, dot W3 (cols spread over lane&15), 16-lane reduce, sigmoid
    const float bb3 = b3[0];
    #pragma unroll
    for (int reg = 0; reg < 4; ++reg) {
        float p = 0.0f;
        #pragma unroll
        for (int nt = 0; nt < 4; ++nt)
            p += fmaxf(acc2[nt][reg], 0.0f) * s_w3[nt * 16 + (lane & 15)];
        p += __shfl_xor(p, 1);
        p += __shfl_xor(p, 2);
        p += __shfl_xor(p, 4);
        p += __shfl_xor(p, 8);
        if ((lane & 15) == 0) {
            int c = c0 + w * 16 + ((lane >> 4) << 2) + reg;
            if (c < C_) scores[c] = 1.0f / (1.0f + expf(-(p + bb3)));
        }
    }
}

// ---------------------------------------------------------------------------
extern "C" void kernel_launch(void* const* d_in, const int* in_sizes, int n_in,
                              void* d_out, int out_size, void* d_ws, size_t ws_size,
                              hipStream_t stream) {
    const float* x        = (const float*)d_in[0];
    const int*   ei       = (const int*)d_in[1];
    const int*   batch    = (const int*)d_in[2];
    const int*   cand     = (const int*)d_in[3];
    const float* c1_W1    = (const float*)d_in[4];
    const float* c1_b1    = (const float*)d_in[5];
    const float* c1_W2    = (const float*)d_in[6];
    const float* c1_b2    = (const float*)d_in[7];
    const float* c1_g     = (const float*)d_in[8];
    const float* c1_be    = (const float*)d_in[9];
    const float* c1_m     = (const float*)d_in[10];
    const float* c1_v     = (const float*)d_in[11];
    const float* c1_eps   = (const float*)d_in[12];
    const float* cs_W1    = (const float*)d_in[13];
    const float* cs_b1    = (const float*)d_in[14];
    const float* cs_W2    = (const float*)d_in[15];
    const float* cs_b2    = (const float*)d_in[16];
    const float* cs_g     = (const float*)d_in[17];
    const float* cs_be    = (const float*)d_in[18];
    const float* cs_m     = (const float*)d_in[19];
    const float* cs_v     = (const float*)d_in[20];
    const float* cs_eps   = (const float*)d_in[21];
    const float* nc_W1    = (const float*)d_in[22];
    const float* nc_b1    = (const float*)d_in[23];
    const float* nc_W2    = (const float*)d_in[24];
    const float* nc_b2    = (const float*)d_in[25];
    const float* nc_W3    = (const float*)d_in[26];
    const float* nc_b3    = (const float*)d_in[27];
    const float* nc_W4    = (const float*)d_in[28];
    const float* nc_b4    = (const float*)d_in[29];
    const float* comp_emb = (const float*)d_in[30];
    const float* ep_W1    = (const float*)d_in[31];
    const float* ep_b1    = (const float*)d_in[32];
    const float* ep_W2    = (const float*)d_in[33];
    const float* ep_b2    = (const float*)d_in[34];
    const float* ep_W3    = (const float*)d_in[35];
    const float* ep_b3    = (const float*)d_in[36];

    const int N_ = in_sizes[0] / 32;
    const int E_ = in_sizes[1] / 2;
    const int C_ = in_sizes[3];
    const int* src = ei;
    const int* dst = ei + E_;

    char* ws = (char*)d_ws;
    size_t off = 0;
    float* agg      = (float*)(ws + off); off += (size_t)N_ * 64 * 4;
    float* node_emb = (float*)(ws + off); off += (size_t)N_ * DD * 4;
    float* gsum     = (float*)(ws + off); off += (size_t)GG * DD * 4;
    float* gcnt     = (float*)(ws + off); off += 1024;
    int*   comp_idx = (int*)(ws + off);   off += 1024;
    float* pc       = (float*)(ws + off); off += NCC * 128 * 4;
    unsigned short* W1b_p = (unsigned short*)(ws + off); off += 6 * 8 * 512 * 2;
    unsigned short* W2_p  = (unsigned short*)(ws + off); off += 4 * 4 * 512 * 2;

    float* class_out = (float*)d_out;          // 256*10
    float* scores    = class_out + GG * NCC;   // 200000

    // ---- edge weight prep (independent of graph pipeline) ----
    prep_edge<<<(6 * 8 * 512 + 4 * 4 * 512 + NCC * 128 + 255) / 256, 256, 0, stream>>>(
        ep_W1, ep_b1, ep_W2, comp_emb, W1b_p, W2_p, pc);

    // ---- GIN layer 1 (K=32) ----
    hipMemsetAsync(agg, 0, (size_t)N_ * 32 * 4, stream);
    scatter_add_k<5><<<(E_ * 32 + 255) / 256, 256, 0, stream>>>(x, 32, src, dst, agg, E_);
    gin_node_mlp<32><<<(N_ + 7) / 8, 512, 0, stream>>>(
        x, 32, agg, c1_W1, c1_b1, c1_W2, c1_b2, c1_g, c1_be, c1_m, c1_v, c1_eps,
        node_emb + 0, DD, N_);

    // ---- GIN layer 2 (K=64) ----
    hipMemsetAsync(agg, 0, (size_t)N_ * 64 * 4, stream);
    scatter_add_k<6><<<(E_ * 64 + 255) / 256, 256, 0, stream>>>(node_emb + 0, DD, src, dst, agg, E_);
    gin_node_mlp<64><<<(N_ + 7) / 8, 512, 0, stream>>>(
        node_emb + 0, DD, agg,
        cs_W1 + 0 * 4096, cs_b1 + 0 * 64, cs_W2 + 0 * 4096, cs_b2 + 0 * 64,
        cs_g + 0 * 64, cs_be + 0 * 64, cs_m + 0 * 64, cs_v + 0 * 64, cs_eps + 0,
        node_emb + 64, DD, N_);

    // ---- GIN layer 3 (K=64) ----
    hipMemsetAsync(agg, 0, (size_t)N_ * 64 * 4, stream);
    scatter_add_k<6><<<(E_ * 64 + 255) / 256, 256, 0, stream>>>(node_emb + 64, DD, src, dst, agg, E_);
    gin_node_mlp<64><<<(N_ + 7) / 8, 512, 0, stream>>>(
        node_emb + 64, DD, agg,
        cs_W1 + 1 * 4096, cs_b1 + 1 * 64, cs_W2 + 1 * 4096, cs_b2 + 1 * 64,
        cs_g + 1 * 64, cs_be + 1 * 64, cs_m + 1 * 64, cs_v + 1 * 64, cs_eps + 1,
        node_emb + 128, DD, N_);

    // ---- mean pool + head ----
    hipMemsetAsync(gsum, 0, (size_t)(GG * DD + GG) * 4, stream);
    pool_kernel<<<(N_ + 255) / 256, 256, 0, stream>>>(node_emb, batch, gsum, gcnt, N_);
    head_kernel<<<GG, 256, 0, stream>>>(gsum, gcnt, nc_W1, nc_b1, nc_W2, nc_b2,
                                        nc_W3, nc_b3, nc_W4, nc_b4, class_out, comp_idx);

    // ---- edge prediction (MFMA) ----
    edge_mfma<<<(C_ + 63) / 64, 256, 0, stream>>>(
        cand, batch, comp_idx, node_emb, W1b_p, W2_p, pc, ep_W3, ep_b3, scores, C_);
}

// Round 3
// 632.962 us; speedup vs baseline: 2.7434x; 1.7192x over previous
//
#include <hip/hip_runtime.h>
#include <hip/hip_bf16.h>

// Problem constants (MultiTaskFEGIN): N=100000, E=1200000, F=32, H=64, L=3,
// G=256, C=200000, NC=10, D=L*H=192.

#define GG 256
#define NCC 10
#define DD 192

typedef short bf16x8 __attribute__((ext_vector_type(8)));
typedef float f32x4  __attribute__((ext_vector_type(4)));

__device__ inline unsigned short f2bf_u(float x) {
    __hip_bfloat16 h = __float2bfloat16(x);
    return *reinterpret_cast<unsigned short*>(&h);
}

// ---------------------------------------------------------------------------
// CSR build: deg histogram -> exclusive scan -> slot scatter of src ids
// ---------------------------------------------------------------------------
__global__ void deg_count(const int* __restrict__ dst, int* __restrict__ deg, int E_) {
    int e = blockIdx.x * 256 + threadIdx.x;
    if (e < E_) atomicAdd(&deg[dst[e]], 1);
}

__global__ void scan1(const int* __restrict__ deg, int* __restrict__ excl,
                      int* __restrict__ bsum, int N_) {
    __shared__ int s[1024];
    const int t = threadIdx.x;
    const int i = blockIdx.x * 1024 + t;
    int v = (i < N_) ? deg[i] : 0;
    s[t] = v;
    __syncthreads();
    for (int off = 1; off < 1024; off <<= 1) {
        int x = (t >= off) ? s[t - off] : 0;
        __syncthreads();
        s[t] += x;
        __syncthreads();
    }
    if (i < N_) excl[i] = s[t] - v;          // exclusive within block
    if (t == 1023) bsum[blockIdx.x] = s[1023];
}

__global__ void scan2(int* __restrict__ bsum, int nb) {
    __shared__ int s[1024];
    const int t = threadIdx.x;
    int v = (t < nb) ? bsum[t] : 0;
    s[t] = v;
    __syncthreads();
    for (int off = 1; off < 1024; off <<= 1) {
        int x = (t >= off) ? s[t - off] : 0;
        __syncthreads();
        s[t] += x;
        __syncthreads();
    }
    if (t < nb) bsum[t] = s[t] - v;          // exclusive block offsets
}

__global__ void scan3(int* __restrict__ rowptr, int* __restrict__ pos,
                      const int* __restrict__ bsum, int N_, int E_) {
    int i = blockIdx.x * 256 + threadIdx.x;
    if (i < N_) {
        int r = rowptr[i] + bsum[i >> 10];
        rowptr[i] = r;
        pos[i] = r;
    } else if (i == N_) {
        rowptr[N_] = E_;
    }
}

__global__ void scatter_csr(const int* __restrict__ src, const int* __restrict__ dst,
                            int* __restrict__ pos, int* __restrict__ nbr, int E_) {
    int e = blockIdx.x * 256 + threadIdx.x;
    if (e < E_) {
        int p = atomicAdd(&pos[dst[e]], 1);
        nbr[p] = src[e];
    }
}

// ---------------------------------------------------------------------------
// Fused GIN layer: per-wave neighbor gather (sum) + 2-layer MLP + BN.
// 32 nodes/block (512 thr, 8 waves, 4 nodes/wave). Activations transposed in
// LDS (s_hinT[k][node], pad 36) so GEMV reads are 1 W-read + 1 b128 broadcast
// per k serving 4 nodes.
// ---------------------------------------------------------------------------
template<int K>
__global__ __launch_bounds__(512) void gin_fused(
    const float* __restrict__ hin, int in_stride,
    const int* __restrict__ rowptr, const int* __restrict__ nbr,
    const float* __restrict__ W1, const float* __restrict__ b1,
    const float* __restrict__ W2, const float* __restrict__ b2,
    const float* __restrict__ gamma, const float* __restrict__ beta,
    const float* __restrict__ mean, const float* __restrict__ var,
    const float* __restrict__ eps_p,
    float* __restrict__ out, int out_stride, int N_) {
    constexpr int NT = 32;
    constexpr int PAD = 36;
    __shared__ float s_hinT[K][PAD];
    __shared__ float s_t1T[64][PAD];
    __shared__ float s_W1[K * 64];
    __shared__ float s_W2[64 * 64];

    const int t = threadIdx.x;
    const int lane = t & 63;
    const int w = t >> 6;
    const int node0 = blockIdx.x * NT;
    const int nb = w * 4;

    // stage weights (float4)
    {
        const float4* W1v = (const float4*)W1;
        float4* s1 = (float4*)s_W1;
        for (int i = t; i < K * 16; i += 512) s1[i] = W1v[i];
        const float4* W2v = (const float4*)W2;
        float4* s2 = (float4*)s_W2;
        for (int i = t; i < 1024; i += 512) s2[i] = W2v[i];
    }

    const float eps1 = 1.0f + eps_p[0];

    // gather: wave w handles nodes node0+nb .. +3
    #pragma unroll
    for (int r = 0; r < 4; ++r) {
        const int li = nb + r;
        const int node = node0 + li;
        if (K == 64) {
            float acc = 0.0f;
            if (node < N_) {
                acc = eps1 * hin[(size_t)node * in_stride + lane];
                int j = rowptr[node];
                const int end = rowptr[node + 1];
                for (; j + 4 <= end; j += 4) {
                    int s0 = nbr[j], s1 = nbr[j + 1], s2 = nbr[j + 2], s3 = nbr[j + 3];
                    float v0 = hin[(size_t)s0 * in_stride + lane];
                    float v1 = hin[(size_t)s1 * in_stride + lane];
                    float v2 = hin[(size_t)s2 * in_stride + lane];
                    float v3 = hin[(size_t)s3 * in_stride + lane];
                    acc += v0 + v1 + v2 + v3;
                }
                for (; j < end; ++j)
                    acc += hin[(size_t)nbr[j] * in_stride + lane];
            }
            s_hinT[lane][li] = acc;
        } else {
            const int d = lane & 31, half = lane >> 5;
            float acc = 0.0f;
            if (node < N_) {
                const int end = rowptr[node + 1];
                for (int j = rowptr[node] + half; j < end; j += 2)
                    acc += hin[(size_t)nbr[j] * in_stride + d];
            }
            acc += __shfl_xor(acc, 32);
            if (node < N_ && half == 0)
                acc += eps1 * hin[(size_t)node * in_stride + d];
            if (half == 0) s_hinT[d][li] = acc;
        }
    }
    __syncthreads();

    // GEMV1: t1 = relu(hin @ W1 + b1) for 4 nodes per thread
    float r0 = b1[lane], r1 = r0, r2 = r0, r3 = r0;
    #pragma unroll 8
    for (int k = 0; k < K; ++k) {
        const float wv = s_W1[k * 64 + lane];
        const float4 h = *(const float4*)&s_hinT[k][nb];
        r0 += h.x * wv; r1 += h.y * wv; r2 += h.z * wv; r3 += h.w * wv;
    }
    {
        float4 o = { fmaxf(r0, 0.f), fmaxf(r1, 0.f), fmaxf(r2, 0.f), fmaxf(r3, 0.f) };
        *(float4*)&s_t1T[lane][nb] = o;   // same-wave producer/consumer: no barrier
    }

    // GEMV2 + BN
    float a0 = b2[lane], a1 = a0, a2 = a0, a3 = a0;
    #pragma unroll 8
    for (int k = 0; k < 64; ++k) {
        const float wv = s_W2[k * 64 + lane];
        const float4 h = *(const float4*)&s_t1T[k][nb];
        a0 += h.x * wv; a1 += h.y * wv; a2 += h.z * wv; a3 += h.w * wv;
    }
    const float ga = gamma[lane], be = beta[lane], mu = mean[lane];
    const float iv = rsqrtf(var[lane] + 1e-5f);
    const int base = node0 + nb;
    if (base + 0 < N_) out[(size_t)(base + 0) * out_stride + lane] = ga * (fmaxf(a0, 0.f) - mu) * iv + be;
    if (base + 1 < N_) out[(size_t)(base + 1) * out_stride + lane] = ga * (fmaxf(a1, 0.f) - mu) * iv + be;
    if (base + 2 < N_) out[(size_t)(base + 2) * out_stride + lane] = ga * (fmaxf(a2, 0.f) - mu) * iv + be;
    if (base + 3 < N_) out[(size_t)(base + 3) * out_stride + lane] = ga * (fmaxf(a3, 0.f) - mu) * iv + be;
}

// ---------------------------------------------------------------------------
// Mean-pool (batch sorted)
// ---------------------------------------------------------------------------
__global__ void pool_kernel(const float* __restrict__ node_emb, const int* __restrict__ batch,
                            float* __restrict__ gsum, float* __restrict__ gcnt, int N_) {
    const int CHUNK = 256;
    __shared__ int sb[CHUNK];
    const int n0 = blockIdx.x * CHUNK;
    const int t  = threadIdx.x;
    const int cnt_local = min(n0 + CHUNK, N_) - n0;
    if (t < cnt_local) sb[t] = batch[n0 + t];
    __syncthreads();
    if (cnt_local <= 0) return;

    if (t < DD) {
        float acc = 0.0f;
        int curg = sb[0];
        for (int n = 0; n < cnt_local; ++n) {
            int g = sb[n];
            if (g != curg) {
                atomicAdd(&gsum[curg * DD + t], acc);
                acc = 0.0f; curg = g;
            }
            acc += node_emb[(long long)(n0 + n) * DD + t];
        }
        atomicAdd(&gsum[curg * DD + t], acc);
    } else if (t == DD) {
        int c = 1, curg = sb[0];
        for (int n = 1; n < cnt_local; ++n) {
            if (sb[n] != curg) {
                atomicAdd(&gcnt[curg], (float)c);
                c = 0; curg = sb[n];
            }
            ++c;
        }
        atomicAdd(&gcnt[curg], (float)c);
    }
}

// ---------------------------------------------------------------------------
// Classification head: one block per graph.
// ---------------------------------------------------------------------------
__global__ void head_kernel(const float* __restrict__ gsum, const float* __restrict__ gcnt,
                            const float* __restrict__ W1, const float* __restrict__ b1,
                            const float* __restrict__ W2, const float* __restrict__ b2,
                            const float* __restrict__ W3, const float* __restrict__ b3,
                            const float* __restrict__ W4, const float* __restrict__ b4,
                            float* __restrict__ class_out, int* __restrict__ comp_idx) {
    const int g = blockIdx.x;
    const int t = threadIdx.x;
    __shared__ float ge[DD], h1[128], h2[64], h3[64], logits[NCC];

    const float c = fmaxf(gcnt[g], 1.0f);
    if (t < DD) ge[t] = gsum[g * DD + t] / c;
    __syncthreads();

    if (t < 128) {
        float a = b1[t];
        #pragma unroll 4
        for (int k = 0; k < DD; ++k) a += ge[k] * W1[k * 128 + t];
        h1[t] = fmaxf(a, 0.0f);
    }
    __syncthreads();
    if (t < 64) {
        float a = b2[t];
        #pragma unroll 4
        for (int k = 0; k < 128; ++k) a += h1[k] * W2[k * 64 + t];
        h2[t] = fmaxf(a, 0.0f);
    }
    __syncthreads();
    if (t < 64) {
        float a = b3[t];
        #pragma unroll 4
        for (int k = 0; k < 64; ++k) a += h2[k] * W3[k * 64 + t];
        h3[t] = fmaxf(a, 0.0f);
    }
    __syncthreads();
    if (t < NCC) {
        float a = b4[t];
        #pragma unroll
        for (int k = 0; k < 64; ++k) a += h3[k] * W4[k * NCC + t];
        logits[t] = a;
    }
    __syncthreads();
    if (t == 0) {
        float mx = logits[0]; int am = 0;
        for (int j = 1; j < NCC; ++j) if (logits[j] > mx) { mx = logits[j]; am = j; }
        float se = 0.0f;
        for (int j = 0; j < NCC; ++j) se += expf(logits[j] - mx);
        float lse = logf(se);
        for (int j = 0; j < NCC; ++j) class_out[g * NCC + j] = logits[j] - mx - lse;
        comp_idx[g] = am;
    }
}

// ---------------------------------------------------------------------------
// prep_edge: pack ep_W1 (rows 192..383) and ep_W2 into MFMA B-fragment order;
// pc[10][128] = comp_emb @ W1a + b1.
// ---------------------------------------------------------------------------
__global__ void prep_edge(const float* __restrict__ W1, const float* __restrict__ b1,
                          const float* __restrict__ W2, const float* __restrict__ comp_emb,
                          unsigned short* __restrict__ W1b_p, unsigned short* __restrict__ W2_p,
                          float* __restrict__ pc) {
    int idx = blockIdx.x * 256 + threadIdx.x;
    const int S1 = 6 * 8 * 512;
    const int S2 = 4 * 4 * 512;
    if (idx < S1) {
        int frag = idx >> 9;
        int lane = (idx >> 3) & 63;
        int j = idx & 7;
        int kstep = frag >> 3, nt = frag & 7;
        int k = kstep * 32 + ((lane >> 4) << 3) + j;
        int n = nt * 16 + (lane & 15);
        W1b_p[idx] = f2bf_u(W1[(192 + k) * 128 + n]);
    } else if (idx < S1 + S2) {
        int i2 = idx - S1;
        int frag = i2 >> 9;
        int lane = (i2 >> 3) & 63;
        int j = i2 & 7;
        int kstep = frag >> 2, nt = frag & 3;
        int k = kstep * 32 + ((lane >> 4) << 3) + j;
        int n = nt * 16 + (lane & 15);
        W2_p[i2] = f2bf_u(W2[k * 64 + n]);
    } else if (idx < S1 + S2 + NCC * 128) {
        int i3 = idx - (S1 + S2);
        int ci = i3 >> 7, col = i3 & 127;
        float a = b1[col];
        for (int k = 0; k < DD; ++k) a += comp_emb[ci * DD + k] * W1[k * 128 + col];
        pc[i3] = a;
    }
}

// ---------------------------------------------------------------------------
// edge_mfma: 64 candidates per 256-thread block (4 waves).
// ---------------------------------------------------------------------------
__global__ __launch_bounds__(256) void edge_mfma(
    const int* __restrict__ cand, const int* __restrict__ batch,
    const int* __restrict__ comp_idx, const float* __restrict__ node_emb,
    const unsigned short* __restrict__ W1b_p, const unsigned short* __restrict__ W2_p,
    const float* __restrict__ pc, const float* __restrict__ W3,
    const float* __restrict__ b3, float* __restrict__ scores, int C_) {
    __shared__ char s_de[64 * 384];
    __shared__ char s_h1[64 * 256];
    __shared__ int s_node[64];
    __shared__ int s_ci[64];
    __shared__ float s_pc[NCC * 128];
    __shared__ float s_w3[64];

    const int t = threadIdx.x;
    const int lane = t & 63;
    const int w = t >> 6;
    const int c0 = blockIdx.x * 64;

    if (t < 64) {
        int c = c0 + t;
        int node = (c < C_) ? cand[c] : cand[0];
        s_node[t] = node;
        s_ci[t] = comp_idx[batch[node]];
        s_w3[t] = W3[t];
    }
    for (int i = t; i < NCC * 128; i += 256) s_pc[i] = pc[i];
    __syncthreads();

    for (int i = t; i < 64 * 48; i += 256) {
        int r = i / 48, c4 = i - r * 48;
        float4 v = *(const float4*)(node_emb + (long long)s_node[r] * DD + c4 * 4);
        ushort4 u;
        u.x = f2bf_u(v.x); u.y = f2bf_u(v.y); u.z = f2bf_u(v.z); u.w = f2bf_u(v.w);
        int off = r * 384 + c4 * 8;
        *(ushort4*)(s_de + (off ^ ((r & 7) << 4))) = u;
    }
    __syncthreads();

    f32x4 acc1[8];
    #pragma unroll
    for (int nt = 0; nt < 8; ++nt) acc1[nt] = (f32x4){0.f, 0.f, 0.f, 0.f};
    const int arow = w * 16 + (lane & 15);
    const int abase = arow * 384 + ((lane >> 4) << 4);
    #pragma unroll
    for (int ks = 0; ks < 6; ++ks) {
        bf16x8 a = *(const bf16x8*)(s_de + ((abase + ks * 64) ^ ((arow & 7) << 4)));
        #pragma unroll
        for (int nt = 0; nt < 8; ++nt) {
            bf16x8 b = *(const bf16x8*)(W1b_p + ((ks * 8 + nt) << 9) + (lane << 3));
            acc1[nt] = __builtin_amdgcn_mfma_f32_16x16x32_bf16(a, b, acc1[nt], 0, 0, 0);
        }
    }
    {
        const int rq = (lane >> 4) << 2;
        #pragma unroll
        for (int reg = 0; reg < 4; ++reg) {
            int row = w * 16 + rq + reg;
            int ci = s_ci[row];
            #pragma unroll
            for (int nt = 0; nt < 8; ++nt) {
                int col = nt * 16 + (lane & 15);
                float v = acc1[nt][reg] + s_pc[ci * 128 + col];
                v = fmaxf(v, 0.0f);
                int off = row * 256 + col * 2;
                *(unsigned short*)(s_h1 + (off ^ ((row & 7) << 4))) = f2bf_u(v);
            }
        }
    }
    __syncthreads();

    f32x4 acc2[4];
    #pragma unroll
    for (int nt = 0; nt < 4; ++nt) acc2[nt] = (f32x4){0.f, 0.f, 0.f, 0.f};
    const int a2base = arow * 256 + ((lane >> 4) << 4);
    #pragma unroll
    for (int ks = 0; ks < 4; ++ks) {
        bf16x8 a = *(const bf16x8*)(s_h1 + ((a2base + ks * 64) ^ ((arow & 7) << 4)));
        #pragma unroll
        for (int nt = 0; nt < 4; ++nt) {
            bf16x8 b = *(const bf16x8*)(W2_p + ((ks * 4 + nt) << 9) + (lane << 3));
            acc2[nt] = __builtin_amdgcn_mfma_f32_16x16x32_bf16(a, b, acc2[nt], 0, 0, 0);
        }
    }
    const float bb3 = b3[0];
    #pragma unroll
    for (int reg = 0; reg < 4; ++reg) {
        float p = 0.0f;
        #pragma unroll
        for (int nt = 0; nt < 4; ++nt)
            p += fmaxf(acc2[nt][reg], 0.0f) * s_w3[nt * 16 + (lane & 15)];
        p += __shfl_xor(p, 1);
        p += __shfl_xor(p, 2);
        p += __shfl_xor(p, 4);
        p += __shfl_xor(p, 8);
        if ((lane & 15) == 0) {
            int c = c0 + w * 16 + ((lane >> 4) << 2) + reg;
            if (c < C_) scores[c] = 1.0f / (1.0f + expf(-(p + bb3)));
        }
    }
}

// ---------------------------------------------------------------------------
extern "C" void kernel_launch(void* const* d_in, const int* in_sizes, int n_in,
                              void* d_out, int out_size, void* d_ws, size_t ws_size,
                              hipStream_t stream) {
    const float* x        = (const float*)d_in[0];
    const int*   ei       = (const int*)d_in[1];
    const int*   batch    = (const int*)d_in[2];
    const int*   cand     = (const int*)d_in[3];
    const float* c1_W1    = (const float*)d_in[4];
    const float* c1_b1    = (const float*)d_in[5];
    const float* c1_W2    = (const float*)d_in[6];
    const float* c1_b2    = (const float*)d_in[7];
    const float* c1_g     = (const float*)d_in[8];
    const float* c1_be    = (const float*)d_in[9];
    const float* c1_m     = (const float*)d_in[10];
    const float* c1_v     = (const float*)d_in[11];
    const float* c1_eps   = (const float*)d_in[12];
    const float* cs_W1    = (const float*)d_in[13];
    const float* cs_b1    = (const float*)d_in[14];
    const float* cs_W2    = (const float*)d_in[15];
    const float* cs_b2    = (const float*)d_in[16];
    const float* cs_g     = (const float*)d_in[17];
    const float* cs_be    = (const float*)d_in[18];
    const float* cs_m     = (const float*)d_in[19];
    const float* cs_v     = (const float*)d_in[20];
    const float* cs_eps   = (const float*)d_in[21];
    const float* nc_W1    = (const float*)d_in[22];
    const float* nc_b1    = (const float*)d_in[23];
    const float* nc_W2    = (const float*)d_in[24];
    const float* nc_b2    = (const float*)d_in[25];
    const float* nc_W3    = (const float*)d_in[26];
    const float* nc_b3    = (const float*)d_in[27];
    const float* nc_W4    = (const float*)d_in[28];
    const float* nc_b4    = (const float*)d_in[29];
    const float* comp_emb = (const float*)d_in[30];
    const float* ep_W1    = (const float*)d_in[31];
    const float* ep_b1    = (const float*)d_in[32];
    const float* ep_W2    = (const float*)d_in[33];
    const float* ep_b2    = (const float*)d_in[34];
    const float* ep_W3    = (const float*)d_in[35];
    const float* ep_b3    = (const float*)d_in[36];

    const int N_ = in_sizes[0] / 32;
    const int E_ = in_sizes[1] / 2;
    const int C_ = in_sizes[3];
    const int* src = ei;
    const int* dst = ei + E_;

    char* ws = (char*)d_ws;
    size_t off = 0;
    float* node_emb = (float*)(ws + off); off += (size_t)N_ * DD * 4;
    int*   rowptr   = (int*)(ws + off);   off += (size_t)(N_ + 2) * 4;
    int*   pos      = (int*)(ws + off);   off += (size_t)N_ * 4;
    int*   deg      = (int*)(ws + off);   off += (size_t)N_ * 4;
    int*   nbr      = (int*)(ws + off);   off += (size_t)E_ * 4;
    int*   bsum     = (int*)(ws + off);   off += 4096;
    float* gsum     = (float*)(ws + off); off += (size_t)GG * DD * 4;
    float* gcnt     = (float*)(ws + off); off += 1024;
    int*   comp_idx = (int*)(ws + off);   off += 1024;
    float* pc       = (float*)(ws + off); off += NCC * 128 * 4;
    unsigned short* W1b_p = (unsigned short*)(ws + off); off += 6 * 8 * 512 * 2;
    unsigned short* W2_p  = (unsigned short*)(ws + off); off += 4 * 4 * 512 * 2;

    float* class_out = (float*)d_out;
    float* scores    = class_out + GG * NCC;

    // ---- edge weight prep (independent) ----
    prep_edge<<<(6 * 8 * 512 + 4 * 4 * 512 + NCC * 128 + 255) / 256, 256, 0, stream>>>(
        ep_W1, ep_b1, ep_W2, comp_emb, W1b_p, W2_p, pc);

    // ---- CSR build (once, reused by all 3 layers) ----
    hipMemsetAsync(deg, 0, (size_t)N_ * 4, stream);
    deg_count<<<(E_ + 255) / 256, 256, 0, stream>>>(dst, deg, E_);
    const int nsb = (N_ + 1023) / 1024;
    scan1<<<nsb, 1024, 0, stream>>>(deg, rowptr, bsum, N_);
    scan2<<<1, 1024, 0, stream>>>(bsum, nsb);
    scan3<<<(N_ + 1 + 255) / 256, 256, 0, stream>>>(rowptr, pos, bsum, N_, E_);
    scatter_csr<<<(E_ + 255) / 256, 256, 0, stream>>>(src, dst, pos, nbr, E_);

    // ---- GIN layers (fused gather + MLP) ----
    const int gblk = (N_ + 31) / 32;
    gin_fused<32><<<gblk, 512, 0, stream>>>(
        x, 32, rowptr, nbr, c1_W1, c1_b1, c1_W2, c1_b2,
        c1_g, c1_be, c1_m, c1_v, c1_eps, node_emb + 0, DD, N_);
    gin_fused<64><<<gblk, 512, 0, stream>>>(
        node_emb + 0, DD, rowptr, nbr,
        cs_W1 + 0 * 4096, cs_b1 + 0 * 64, cs_W2 + 0 * 4096, cs_b2 + 0 * 64,
        cs_g + 0 * 64, cs_be + 0 * 64, cs_m + 0 * 64, cs_v + 0 * 64, cs_eps + 0,
        node_emb + 64, DD, N_);
    gin_fused<64><<<gblk, 512, 0, stream>>>(
        node_emb + 64, DD, rowptr, nbr,
        cs_W1 + 1 * 4096, cs_b1 + 1 * 64, cs_W2 + 1 * 4096, cs_b2 + 1 * 64,
        cs_g + 1 * 64, cs_be + 1 * 64, cs_m + 1 * 64, cs_v + 1 * 64, cs_eps + 1,
        node_emb + 128, DD, N_);

    // ---- mean pool + head ----
    hipMemsetAsync(gsum, 0, (size_t)(GG * DD + GG) * 4, stream);
    pool_kernel<<<(N_ + 255) / 256, 256, 0, stream>>>(node_emb, batch, gsum, gcnt, N_);
    head_kernel<<<GG, 256, 0, stream>>>(gsum, gcnt, nc_W1, nc_b1, nc_W2, nc_b2,
                                        nc_W3, nc_b3, nc_W4, nc_b4, class_out, comp_idx);

    // ---- edge prediction (MFMA) ----
    edge_mfma<<<(C_ + 63) / 64, 256, 0, stream>>>(
        cand, batch, comp_idx, node_emb, W1b_p, W2_p, pc, ep_W3, ep_b3, scores, C_);
}

// Round 4
// 631.602 us; speedup vs baseline: 2.7493x; 1.0022x over previous
//
#include <hip/hip_runtime.h>
#include <hip/hip_bf16.h>

// Problem constants (MultiTaskFEGIN): N=100000, E=1200000, F=32, H=64, L=3,
// G=256, C=200000, NC=10, D=L*H=192.

#define GG 256
#define NCC 10
#define DD 192

typedef short bf16x8 __attribute__((ext_vector_type(8)));
typedef float f32x4  __attribute__((ext_vector_type(4)));

__device__ inline unsigned short f2bf_u(float x) {
    __hip_bfloat16 h = __float2bfloat16(x);
    return *reinterpret_cast<unsigned short*>(&h);
}

// ---------------------------------------------------------------------------
// CSR build: deg histogram -> exclusive scan -> slot scatter of src ids
// ---------------------------------------------------------------------------
__global__ void deg_count(const int* __restrict__ dst, int* __restrict__ deg, int E_) {
    int e = blockIdx.x * 256 + threadIdx.x;
    if (e < E_) atomicAdd(&deg[dst[e]], 1);
}

__global__ void scan1(const int* __restrict__ deg, int* __restrict__ excl,
                      int* __restrict__ bsum, int N_) {
    __shared__ int s[1024];
    const int t = threadIdx.x;
    const int i = blockIdx.x * 1024 + t;
    int v = (i < N_) ? deg[i] : 0;
    s[t] = v;
    __syncthreads();
    for (int off = 1; off < 1024; off <<= 1) {
        int x = (t >= off) ? s[t - off] : 0;
        __syncthreads();
        s[t] += x;
        __syncthreads();
    }
    if (i < N_) excl[i] = s[t] - v;          // exclusive within block
    if (t == 1023) bsum[blockIdx.x] = s[1023];
}

__global__ void scan2(int* __restrict__ bsum, int nb) {
    __shared__ int s[1024];
    const int t = threadIdx.x;
    int v = (t < nb) ? bsum[t] : 0;
    s[t] = v;
    __syncthreads();
    for (int off = 1; off < 1024; off <<= 1) {
        int x = (t >= off) ? s[t - off] : 0;
        __syncthreads();
        s[t] += x;
        __syncthreads();
    }
    if (t < nb) bsum[t] = s[t] - v;          // exclusive block offsets
}

__global__ void scan3(int* __restrict__ rowptr, int* __restrict__ pos,
                      const int* __restrict__ bsum, int N_, int E_) {
    int i = blockIdx.x * 256 + threadIdx.x;
    if (i < N_) {
        int r = rowptr[i] + bsum[i >> 10];
        rowptr[i] = r;
        pos[i] = r;
    } else if (i == N_) {
        rowptr[N_] = E_;
    }
}

__global__ void scatter_csr(const int* __restrict__ src, const int* __restrict__ dst,
                            int* __restrict__ pos, int* __restrict__ nbr, int E_) {
    int e = blockIdx.x * 256 + threadIdx.x;
    if (e < E_) {
        int p = atomicAdd(&pos[dst[e]], 1);
        nbr[p] = src[e];
    }
}

// ---------------------------------------------------------------------------
// Fused GIN layer: per-wave neighbor gather (sum) + 2-layer MLP + BN.
// 32 nodes/block (512 thr, 8 waves, 4 nodes/wave). BGATHER: aggregate
// neighbors from bf16 hb rows (128B = 1 line each); own-node term fp32.
// Writes fp32 node_emb slice (pool/own-row) + bf16 hb slice (gather/edge).
// ---------------------------------------------------------------------------
template<int K, bool BGATHER>
__global__ __launch_bounds__(512) void gin_fused(
    const float* __restrict__ hin, int in_stride,
    const __hip_bfloat16* __restrict__ hin_b,      // slice ptr, stride DD
    const int* __restrict__ rowptr, const int* __restrict__ nbr,
    const float* __restrict__ W1, const float* __restrict__ b1,
    const float* __restrict__ W2, const float* __restrict__ b2,
    const float* __restrict__ gamma, const float* __restrict__ beta,
    const float* __restrict__ mean, const float* __restrict__ var,
    const float* __restrict__ eps_p,
    float* __restrict__ out, int out_stride,
    __hip_bfloat16* __restrict__ out_b,            // slice ptr, stride DD
    int N_) {
    constexpr int NT = 32;
    constexpr int PAD = 36;
    __shared__ float s_hinT[K][PAD];
    __shared__ float s_t1T[64][PAD];
    __shared__ float s_W1[K * 64];
    __shared__ float s_W2[64 * 64];

    const int t = threadIdx.x;
    const int lane = t & 63;
    const int w = t >> 6;
    const int node0 = blockIdx.x * NT;
    const int nb = w * 4;

    // stage weights (float4)
    {
        const float4* W1v = (const float4*)W1;
        float4* s1 = (float4*)s_W1;
        for (int i = t; i < K * 16; i += 512) s1[i] = W1v[i];
        const float4* W2v = (const float4*)W2;
        float4* s2 = (float4*)s_W2;
        for (int i = t; i < 1024; i += 512) s2[i] = W2v[i];
    }

    const float eps1 = 1.0f + eps_p[0];

    // gather: wave w handles nodes node0+nb .. +3
    #pragma unroll
    for (int r = 0; r < 4; ++r) {
        const int li = nb + r;
        const int node = node0 + li;
        if (K == 64) {
            float acc = 0.0f;
            if (node < N_) {
                acc = eps1 * hin[(size_t)node * in_stride + lane];
                int j = rowptr[node];
                const int end = rowptr[node + 1];
                if (BGATHER) {
                    const __hip_bfloat16* hbp = hin_b + lane;
                    for (; j + 8 <= end; j += 8) {
                        int s0 = nbr[j],     s1 = nbr[j + 1], s2 = nbr[j + 2], s3 = nbr[j + 3];
                        int s4 = nbr[j + 4], s5 = nbr[j + 5], s6 = nbr[j + 6], s7 = nbr[j + 7];
                        float v0 = __bfloat162float(hbp[(size_t)s0 * DD]);
                        float v1 = __bfloat162float(hbp[(size_t)s1 * DD]);
                        float v2 = __bfloat162float(hbp[(size_t)s2 * DD]);
                        float v3 = __bfloat162float(hbp[(size_t)s3 * DD]);
                        float v4 = __bfloat162float(hbp[(size_t)s4 * DD]);
                        float v5 = __bfloat162float(hbp[(size_t)s5 * DD]);
                        float v6 = __bfloat162float(hbp[(size_t)s6 * DD]);
                        float v7 = __bfloat162float(hbp[(size_t)s7 * DD]);
                        acc += ((v0 + v1) + (v2 + v3)) + ((v4 + v5) + (v6 + v7));
                    }
                    for (; j < end; ++j)
                        acc += __bfloat162float(hbp[(size_t)nbr[j] * DD]);
                } else {
                    for (; j + 4 <= end; j += 4) {
                        int s0 = nbr[j], s1 = nbr[j + 1], s2 = nbr[j + 2], s3 = nbr[j + 3];
                        float v0 = hin[(size_t)s0 * in_stride + lane];
                        float v1 = hin[(size_t)s1 * in_stride + lane];
                        float v2 = hin[(size_t)s2 * in_stride + lane];
                        float v3 = hin[(size_t)s3 * in_stride + lane];
                        acc += v0 + v1 + v2 + v3;
                    }
                    for (; j < end; ++j)
                        acc += hin[(size_t)nbr[j] * in_stride + lane];
                }
            }
            s_hinT[lane][li] = acc;
        } else {
            const int d = lane & 31, half = lane >> 5;
            float acc = 0.0f;
            if (node < N_) {
                const int end = rowptr[node + 1];
                for (int j = rowptr[node] + half; j < end; j += 2)
                    acc += hin[(size_t)nbr[j] * in_stride + d];
            }
            acc += __shfl_xor(acc, 32);
            if (node < N_ && half == 0)
                acc += eps1 * hin[(size_t)node * in_stride + d];
            if (half == 0) s_hinT[d][li] = acc;
        }
    }
    __syncthreads();

    // GEMV1: t1 = relu(hin @ W1 + b1) for 4 nodes per thread
    float r0 = b1[lane], r1 = r0, r2 = r0, r3 = r0;
    #pragma unroll 8
    for (int k = 0; k < K; ++k) {
        const float wv = s_W1[k * 64 + lane];
        const float4 h = *(const float4*)&s_hinT[k][nb];
        r0 += h.x * wv; r1 += h.y * wv; r2 += h.z * wv; r3 += h.w * wv;
    }
    {
        float4 o = { fmaxf(r0, 0.f), fmaxf(r1, 0.f), fmaxf(r2, 0.f), fmaxf(r3, 0.f) };
        *(float4*)&s_t1T[lane][nb] = o;   // same-wave producer/consumer: no barrier
    }

    // GEMV2 + BN
    float a0 = b2[lane], a1 = a0, a2 = a0, a3 = a0;
    #pragma unroll 8
    for (int k = 0; k < 64; ++k) {
        const float wv = s_W2[k * 64 + lane];
        const float4 h = *(const float4*)&s_t1T[k][nb];
        a0 += h.x * wv; a1 += h.y * wv; a2 += h.z * wv; a3 += h.w * wv;
    }
    const float ga = gamma[lane], be = beta[lane], mu = mean[lane];
    const float iv = rsqrtf(var[lane] + 1e-5f);
    const int base = node0 + nb;
    float o0 = ga * (fmaxf(a0, 0.f) - mu) * iv + be;
    float o1 = ga * (fmaxf(a1, 0.f) - mu) * iv + be;
    float o2 = ga * (fmaxf(a2, 0.f) - mu) * iv + be;
    float o3 = ga * (fmaxf(a3, 0.f) - mu) * iv + be;
    if (base + 0 < N_) { out[(size_t)(base + 0) * out_stride + lane] = o0; out_b[(size_t)(base + 0) * DD + lane] = __float2bfloat16(o0); }
    if (base + 1 < N_) { out[(size_t)(base + 1) * out_stride + lane] = o1; out_b[(size_t)(base + 1) * DD + lane] = __float2bfloat16(o1); }
    if (base + 2 < N_) { out[(size_t)(base + 2) * out_stride + lane] = o2; out_b[(size_t)(base + 2) * DD + lane] = __float2bfloat16(o2); }
    if (base + 3 < N_) { out[(size_t)(base + 3) * out_stride + lane] = o3; out_b[(size_t)(base + 3) * DD + lane] = __float2bfloat16(o3); }
}

// ---------------------------------------------------------------------------
// Mean-pool (batch sorted) — fp32 node_emb (keeps logits near-fp32)
// ---------------------------------------------------------------------------
__global__ void pool_kernel(const float* __restrict__ node_emb, const int* __restrict__ batch,
                            float* __restrict__ gsum, float* __restrict__ gcnt, int N_) {
    const int CHUNK = 256;
    __shared__ int sb[CHUNK];
    const int n0 = blockIdx.x * CHUNK;
    const int t  = threadIdx.x;
    const int cnt_local = min(n0 + CHUNK, N_) - n0;
    if (t < cnt_local) sb[t] = batch[n0 + t];
    __syncthreads();
    if (cnt_local <= 0) return;

    if (t < DD) {
        float acc = 0.0f;
        int curg = sb[0];
        for (int n = 0; n < cnt_local; ++n) {
            int g = sb[n];
            if (g != curg) {
                atomicAdd(&gsum[curg * DD + t], acc);
                acc = 0.0f; curg = g;
            }
            acc += node_emb[(long long)(n0 + n) * DD + t];
        }
        atomicAdd(&gsum[curg * DD + t], acc);
    } else if (t == DD) {
        int c = 1, curg = sb[0];
        for (int n = 1; n < cnt_local; ++n) {
            if (sb[n] != curg) {
                atomicAdd(&gcnt[curg], (float)c);
                c = 0; curg = sb[n];
            }
            ++c;
        }
        atomicAdd(&gcnt[curg], (float)c);
    }
}

// ---------------------------------------------------------------------------
// Classification head: one block per graph.
// ---------------------------------------------------------------------------
__global__ void head_kernel(const float* __restrict__ gsum, const float* __restrict__ gcnt,
                            const float* __restrict__ W1, const float* __restrict__ b1,
                            const float* __restrict__ W2, const float* __restrict__ b2,
                            const float* __restrict__ W3, const float* __restrict__ b3,
                            const float* __restrict__ W4, const float* __restrict__ b4,
                            float* __restrict__ class_out, int* __restrict__ comp_idx) {
    const int g = blockIdx.x;
    const int t = threadIdx.x;
    __shared__ float ge[DD], h1[128], h2[64], h3[64], logits[NCC];

    const float c = fmaxf(gcnt[g], 1.0f);
    if (t < DD) ge[t] = gsum[g * DD + t] / c;
    __syncthreads();

    if (t < 128) {
        float a = b1[t];
        #pragma unroll 4
        for (int k = 0; k < DD; ++k) a += ge[k] * W1[k * 128 + t];
        h1[t] = fmaxf(a, 0.0f);
    }
    __syncthreads();
    if (t < 64) {
        float a = b2[t];
        #pragma unroll 4
        for (int k = 0; k < 128; ++k) a += h1[k] * W2[k * 64 + t];
        h2[t] = fmaxf(a, 0.0f);
    }
    __syncthreads();
    if (t < 64) {
        float a = b3[t];
        #pragma unroll 4
        for (int k = 0; k < 64; ++k) a += h2[k] * W3[k * 64 + t];
        h3[t] = fmaxf(a, 0.0f);
    }
    __syncthreads();
    if (t < NCC) {
        float a = b4[t];
        #pragma unroll
        for (int k = 0; k < 64; ++k) a += h3[k] * W4[k * NCC + t];
        logits[t] = a;
    }
    __syncthreads();
    if (t == 0) {
        float mx = logits[0]; int am = 0;
        for (int j = 1; j < NCC; ++j) if (logits[j] > mx) { mx = logits[j]; am = j; }
        float se = 0.0f;
        for (int j = 0; j < NCC; ++j) se += expf(logits[j] - mx);
        float lse = logf(se);
        for (int j = 0; j < NCC; ++j) class_out[g * NCC + j] = logits[j] - mx - lse;
        comp_idx[g] = am;
    }
}

// ---------------------------------------------------------------------------
// prep_edge: pack ep_W1 (rows 192..383) and ep_W2 into MFMA B-fragment order;
// pc[10][128] = comp_emb @ W1a + b1.
// ---------------------------------------------------------------------------
__global__ void prep_edge(const float* __restrict__ W1, const float* __restrict__ b1,
                          const float* __restrict__ W2, const float* __restrict__ comp_emb,
                          unsigned short* __restrict__ W1b_p, unsigned short* __restrict__ W2_p,
                          float* __restrict__ pc) {
    int idx = blockIdx.x * 256 + threadIdx.x;
    const int S1 = 6 * 8 * 512;
    const int S2 = 4 * 4 * 512;
    if (idx < S1) {
        int frag = idx >> 9;
        int lane = (idx >> 3) & 63;
        int j = idx & 7;
        int kstep = frag >> 3, nt = frag & 7;
        int k = kstep * 32 + ((lane >> 4) << 3) + j;
        int n = nt * 16 + (lane & 15);
        W1b_p[idx] = f2bf_u(W1[(192 + k) * 128 + n]);
    } else if (idx < S1 + S2) {
        int i2 = idx - S1;
        int frag = i2 >> 9;
        int lane = (i2 >> 3) & 63;
        int j = i2 & 7;
        int kstep = frag >> 2, nt = frag & 3;
        int k = kstep * 32 + ((lane >> 4) << 3) + j;
        int n = nt * 16 + (lane & 15);
        W2_p[i2] = f2bf_u(W2[k * 64 + n]);
    } else if (idx < S1 + S2 + NCC * 128) {
        int i3 = idx - (S1 + S2);
        int ci = i3 >> 7, col = i3 & 127;
        float a = b1[col];
        for (int k = 0; k < DD; ++k) a += comp_emb[ci * DD + k] * W1[k * 128 + col];
        pc[i3] = a;
    }
}

// ---------------------------------------------------------------------------
// edge_mfma: 64 candidates per 256-thread block (4 waves). de rows gathered
// directly from bf16 hb (384B/row, no conversion).
// ---------------------------------------------------------------------------
__global__ __launch_bounds__(256) void edge_mfma(
    const int* __restrict__ cand, const int* __restrict__ batch,
    const int* __restrict__ comp_idx, const short* __restrict__ hb,
    const unsigned short* __restrict__ W1b_p, const unsigned short* __restrict__ W2_p,
    const float* __restrict__ pc, const float* __restrict__ W3,
    const float* __restrict__ b3, float* __restrict__ scores, int C_) {
    __shared__ char s_de[64 * 384];
    __shared__ char s_h1[64 * 256];
    __shared__ int s_node[64];
    __shared__ int s_ci[64];
    __shared__ float s_pc[NCC * 128];
    __shared__ float s_w3[64];

    const int t = threadIdx.x;
    const int lane = t & 63;
    const int w = t >> 6;
    const int c0 = blockIdx.x * 64;

    if (t < 64) {
        int c = c0 + t;
        int node = (c < C_) ? cand[c] : cand[0];
        s_node[t] = node;
        s_ci[t] = comp_idx[batch[node]];
        s_w3[t] = W3[t];
    }
    for (int i = t; i < NCC * 128; i += 256) s_pc[i] = pc[i];
    __syncthreads();

    // gather de rows (bf16) -> swizzled LDS; 24 x 16B chunks per row
    for (int i = t; i < 64 * 24; i += 256) {
        int r = i / 24, c8 = i - r * 24;
        bf16x8 v = *(const bf16x8*)(hb + (size_t)s_node[r] * DD + c8 * 8);
        int off = r * 384 + c8 * 16;
        *(bf16x8*)(s_de + (off ^ ((r & 7) << 4))) = v;
    }
    __syncthreads();

    f32x4 acc1[8];
    #pragma unroll
    for (int nt = 0; nt < 8; ++nt) acc1[nt] = (f32x4){0.f, 0.f, 0.f, 0.f};
    const int arow = w * 16 + (lane & 15);
    const int abase = arow * 384 + ((lane >> 4) << 4);
    #pragma unroll
    for (int ks = 0; ks < 6; ++ks) {
        bf16x8 a = *(const bf16x8*)(s_de + ((abase + ks * 64) ^ ((arow & 7) << 4)));
        #pragma unroll
        for (int nt = 0; nt < 8; ++nt) {
            bf16x8 b = *(const bf16x8*)(W1b_p + ((ks * 8 + nt) << 9) + (lane << 3));
            acc1[nt] = __builtin_amdgcn_mfma_f32_16x16x32_bf16(a, b, acc1[nt], 0, 0, 0);
        }
    }
    {
        const int rq = (lane >> 4) << 2;
        #pragma unroll
        for (int reg = 0; reg < 4; ++reg) {
            int row = w * 16 + rq + reg;
            int ci = s_ci[row];
            #pragma unroll
            for (int nt = 0; nt < 8; ++nt) {
                int col = nt * 16 + (lane & 15);
                float v = acc1[nt][reg] + s_pc[ci * 128 + col];
                v = fmaxf(v, 0.0f);
                int off = row * 256 + col * 2;
                *(unsigned short*)(s_h1 + (off ^ ((row & 7) << 4))) = f2bf_u(v);
            }
        }
    }
    __syncthreads();

    f32x4 acc2[4];
    #pragma unroll
    for (int nt = 0; nt < 4; ++nt) acc2[nt] = (f32x4){0.f, 0.f, 0.f, 0.f};
    const int a2base = arow * 256 + ((lane >> 4) << 4);
    #pragma unroll
    for (int ks = 0; ks < 4; ++ks) {
        bf16x8 a = *(const bf16x8*)(s_h1 + ((a2base + ks * 64) ^ ((arow & 7) << 4)));
        #pragma unroll
        for (int nt = 0; nt < 4; ++nt) {
            bf16x8 b = *(const bf16x8*)(W2_p + ((ks * 4 + nt) << 9) + (lane << 3));
            acc2[nt] = __builtin_amdgcn_mfma_f32_16x16x32_bf16(a, b, acc2[nt], 0, 0, 0);
        }
    }
    const float bb3 = b3[0];
    #pragma unroll
    for (int reg = 0; reg < 4; ++reg) {
        float p = 0.0f;
        #pragma unroll
        for (int nt = 0; nt < 4; ++nt)
            p += fmaxf(acc2[nt][reg], 0.0f) * s_w3[nt * 16 + (lane & 15)];
        p += __shfl_xor(p, 1);
        p += __shfl_xor(p, 2);
        p += __shfl_xor(p, 4);
        p += __shfl_xor(p, 8);
        if ((lane & 15) == 0) {
            int c = c0 + w * 16 + ((lane >> 4) << 2) + reg;
            if (c < C_) scores[c] = 1.0f / (1.0f + expf(-(p + bb3)));
        }
    }
}

// ---------------------------------------------------------------------------
extern "C" void kernel_launch(void* const* d_in, const int* in_sizes, int n_in,
                              void* d_out, int out_size, void* d_ws, size_t ws_size,
                              hipStream_t stream) {
    const float* x        = (const float*)d_in[0];
    const int*   ei       = (const int*)d_in[1];
    const int*   batch    = (const int*)d_in[2];
    const int*   cand     = (const int*)d_in[3];
    const float* c1_W1    = (const float*)d_in[4];
    const float* c1_b1    = (const float*)d_in[5];
    const float* c1_W2    = (const float*)d_in[6];
    const float* c1_b2    = (const float*)d_in[7];
    const float* c1_g     = (const float*)d_in[8];
    const float* c1_be    = (const float*)d_in[9];
    const float* c1_m     = (const float*)d_in[10];
    const float* c1_v     = (const float*)d_in[11];
    const float* c1_eps   = (const float*)d_in[12];
    const float* cs_W1    = (const float*)d_in[13];
    const float* cs_b1    = (const float*)d_in[14];
    const float* cs_W2    = (const float*)d_in[15];
    const float* cs_b2    = (const float*)d_in[16];
    const float* cs_g     = (const float*)d_in[17];
    const float* cs_be    = (const float*)d_in[18];
    const float* cs_m     = (const float*)d_in[19];
    const float* cs_v     = (const float*)d_in[20];
    const float* cs_eps   = (const float*)d_in[21];
    const float* nc_W1    = (const float*)d_in[22];
    const float* nc_b1    = (const float*)d_in[23];
    const float* nc_W2    = (const float*)d_in[24];
    const float* nc_b2    = (const float*)d_in[25];
    const float* nc_W3    = (const float*)d_in[26];
    const float* nc_b3    = (const float*)d_in[27];
    const float* nc_W4    = (const float*)d_in[28];
    const float* nc_b4    = (const float*)d_in[29];
    const float* comp_emb = (const float*)d_in[30];
    const float* ep_W1    = (const float*)d_in[31];
    const float* ep_b1    = (const float*)d_in[32];
    const float* ep_W2    = (const float*)d_in[33];
    const float* ep_b2    = (const float*)d_in[34];
    const float* ep_W3    = (const float*)d_in[35];
    const float* ep_b3    = (const float*)d_in[36];

    const int N_ = in_sizes[0] / 32;
    const int E_ = in_sizes[1] / 2;
    const int C_ = in_sizes[3];
    const int* src = ei;
    const int* dst = ei + E_;

    char* ws = (char*)d_ws;
    size_t off = 0;
    float* node_emb = (float*)(ws + off); off += (size_t)N_ * DD * 4;
    __hip_bfloat16* hb = (__hip_bfloat16*)(ws + off); off += (size_t)N_ * DD * 2;
    int*   rowptr   = (int*)(ws + off);   off += (size_t)(N_ + 2) * 4;
    int*   pos      = (int*)(ws + off);   off += (size_t)N_ * 4;
    int*   deg      = (int*)(ws + off);   off += (size_t)N_ * 4;
    int*   nbr      = (int*)(ws + off);   off += (size_t)E_ * 4;
    int*   bsum     = (int*)(ws + off);   off += 4096;
    float* gsum     = (float*)(ws + off); off += (size_t)GG * DD * 4;
    float* gcnt     = (float*)(ws + off); off += 1024;
    int*   comp_idx = (int*)(ws + off);   off += 1024;
    float* pc       = (float*)(ws + off); off += NCC * 128 * 4;
    unsigned short* W1b_p = (unsigned short*)(ws + off); off += 6 * 8 * 512 * 2;
    unsigned short* W2_p  = (unsigned short*)(ws + off); off += 4 * 4 * 512 * 2;

    float* class_out = (float*)d_out;
    float* scores    = class_out + GG * NCC;

    // ---- edge weight prep (independent) ----
    prep_edge<<<(6 * 8 * 512 + 4 * 4 * 512 + NCC * 128 + 255) / 256, 256, 0, stream>>>(
        ep_W1, ep_b1, ep_W2, comp_emb, W1b_p, W2_p, pc);

    // ---- CSR build (once, reused by all 3 layers) ----
    hipMemsetAsync(deg, 0, (size_t)N_ * 4, stream);
    deg_count<<<(E_ + 255) / 256, 256, 0, stream>>>(dst, deg, E_);
    const int nsb = (N_ + 1023) / 1024;
    scan1<<<nsb, 1024, 0, stream>>>(deg, rowptr, bsum, N_);
    scan2<<<1, 1024, 0, stream>>>(bsum, nsb);
    scan3<<<(N_ + 1 + 255) / 256, 256, 0, stream>>>(rowptr, pos, bsum, N_, E_);
    scatter_csr<<<(E_ + 255) / 256, 256, 0, stream>>>(src, dst, pos, nbr, E_);

    // ---- GIN layers (fused gather + MLP) ----
    const int gblk = (N_ + 31) / 32;
    gin_fused<32, false><<<gblk, 512, 0, stream>>>(
        x, 32, nullptr, rowptr, nbr, c1_W1, c1_b1, c1_W2, c1_b2,
        c1_g, c1_be, c1_m, c1_v, c1_eps, node_emb + 0, DD, hb + 0, N_);
    gin_fused<64, true><<<gblk, 512, 0, stream>>>(
        node_emb + 0, DD, hb + 0, rowptr, nbr,
        cs_W1 + 0 * 4096, cs_b1 + 0 * 64, cs_W2 + 0 * 4096, cs_b2 + 0 * 64,
        cs_g + 0 * 64, cs_be + 0 * 64, cs_m + 0 * 64, cs_v + 0 * 64, cs_eps + 0,
        node_emb + 64, DD, hb + 64, N_);
    gin_fused<64, true><<<gblk, 512, 0, stream>>>(
        node_emb + 64, DD, hb + 64, rowptr, nbr,
        cs_W1 + 1 * 4096, cs_b1 + 1 * 64, cs_W2 + 1 * 4096, cs_b2 + 1 * 64,
        cs_g + 1 * 64, cs_be + 1 * 64, cs_m + 1 * 64, cs_v + 1 * 64, cs_eps + 1,
        node_emb + 128, DD, hb + 128, N_);

    // ---- mean pool + head ----
    hipMemsetAsync(gsum, 0, (size_t)(GG * DD + GG) * 4, stream);
    pool_kernel<<<(N_ + 255) / 256, 256, 0, stream>>>(node_emb, batch, gsum, gcnt, N_);
    head_kernel<<<GG, 256, 0, stream>>>(gsum, gcnt, nc_W1, nc_b1, nc_W2, nc_b2,
                                        nc_W3, nc_b3, nc_W4, nc_b4, class_out, comp_idx);

    // ---- edge prediction (MFMA) ----
    edge_mfma<<<(C_ + 63) / 64, 256, 0, stream>>>(
        cand, batch, comp_idx, (const short*)hb, W1b_p, W2_p, pc, ep_W3, ep_b3, scores, C_);
}

// Round 5
// 520.627 us; speedup vs baseline: 3.3353x; 1.2132x over previous
//
#include <hip/hip_runtime.h>
#include <hip/hip_bf16.h>

// Problem constants (MultiTaskFEGIN): N=100000, E=1200000, F=32, H=64, L=3,
// G=256, C=200000, NC=10, D=L*H=192.

#define GG 256
#define NCC 10
#define DD 192

typedef short bf16x8 __attribute__((ext_vector_type(8)));
typedef float f32x4  __attribute__((ext_vector_type(4)));

__device__ inline unsigned short f2bf_u(float x) {
    __hip_bfloat16 h = __float2bfloat16(x);
    return *reinterpret_cast<unsigned short*>(&h);
}

// ---------------------------------------------------------------------------
// CSR build: deg histogram -> exclusive scan -> slot scatter of src ids
// ---------------------------------------------------------------------------
__global__ void deg_count(const int* __restrict__ dst, int* __restrict__ deg, int E_) {
    int e = blockIdx.x * 256 + threadIdx.x;
    if (e < E_) atomicAdd(&deg[dst[e]], 1);
}

__global__ void scan1(const int* __restrict__ deg, int* __restrict__ excl,
                      int* __restrict__ bsum, int N_) {
    __shared__ int s[1024];
    const int t = threadIdx.x;
    const int i = blockIdx.x * 1024 + t;
    int v = (i < N_) ? deg[i] : 0;
    s[t] = v;
    __syncthreads();
    for (int off = 1; off < 1024; off <<= 1) {
        int x = (t >= off) ? s[t - off] : 0;
        __syncthreads();
        s[t] += x;
        __syncthreads();
    }
    if (i < N_) excl[i] = s[t] - v;          // exclusive within block
    if (t == 1023) bsum[blockIdx.x] = s[1023];
}

__global__ void scan2(int* __restrict__ bsum, int nb) {
    __shared__ int s[1024];
    const int t = threadIdx.x;
    int v = (t < nb) ? bsum[t] : 0;
    s[t] = v;
    __syncthreads();
    for (int off = 1; off < 1024; off <<= 1) {
        int x = (t >= off) ? s[t - off] : 0;
        __syncthreads();
        s[t] += x;
        __syncthreads();
    }
    if (t < nb) bsum[t] = s[t] - v;          // exclusive block offsets
}

__global__ void scan3(int* __restrict__ rowptr, int* __restrict__ pos,
                      const int* __restrict__ bsum, int N_, int E_) {
    int i = blockIdx.x * 256 + threadIdx.x;
    if (i < N_) {
        int r = rowptr[i] + bsum[i >> 10];
        rowptr[i] = r;
        pos[i] = r;
    } else if (i == N_) {
        rowptr[N_] = E_;
    }
}

__global__ void scatter_csr(const int* __restrict__ src, const int* __restrict__ dst,
                            int* __restrict__ pos, int* __restrict__ nbr, int E_) {
    int e = blockIdx.x * 256 + threadIdx.x;
    if (e < E_) {
        int p = atomicAdd(&pos[dst[e]], 1);
        nbr[p] = src[e];
    }
}

// ---------------------------------------------------------------------------
// Fused GIN layer: combined-span chunked gather (deep ILP) + 2-layer MLP + BN.
// 32 nodes/block (512 thr, 8 waves, 4 consecutive nodes/wave). The wave's 4
// CSR spans are one contiguous range [rowptr[n], rowptr[n+4]): walk it in
// 16-edge chunks, all row loads independent, ownership via 3 uniform boundary
// compares. Index chunk prefetched one ahead (breaks idx->row chain).
// K=64: bf16 rows (128B aligned, 1 line). K=32: fp32 rows, 2 rows per load.
// nbr[] must be padded with >=32 zeroed ints past E.
// ---------------------------------------------------------------------------
template<int K>
__global__ __launch_bounds__(512) void gin_fused(
    const float* __restrict__ hin, int in_stride,
    const __hip_bfloat16* __restrict__ hin_b,      // slice ptr, stride DD (K=64)
    const int* __restrict__ rowptr, const int* __restrict__ nbr,
    const float* __restrict__ W1, const float* __restrict__ b1,
    const float* __restrict__ W2, const float* __restrict__ b2,
    const float* __restrict__ gamma, const float* __restrict__ beta,
    const float* __restrict__ mean, const float* __restrict__ var,
    const float* __restrict__ eps_p,
    float* __restrict__ out, int out_stride,
    __hip_bfloat16* __restrict__ out_b,            // slice ptr, stride DD
    int N_) {
    constexpr int NT = 32;
    constexpr int PAD = 36;
    __shared__ float s_hinT[K][PAD];
    __shared__ float s_t1T[64][PAD];
    __shared__ float s_W1[K * 64];
    __shared__ float s_W2[64 * 64];

    const int t = threadIdx.x;
    const int lane = t & 63;
    const int w = t >> 6;
    const int node0 = blockIdx.x * NT;
    const int nb = w * 4;

    // stage weights (float4)
    {
        const float4* W1v = (const float4*)W1;
        float4* s1 = (float4*)s_W1;
        for (int i = t; i < K * 16; i += 512) s1[i] = W1v[i];
        const float4* W2v = (const float4*)W2;
        float4* s2 = (float4*)s_W2;
        for (int i = t; i < 1024; i += 512) s2[i] = W2v[i];
    }

    const float eps1 = 1.0f + eps_p[0];

    // ---- combined-span gather for this wave's 4 nodes ----
    const int n0w = node0 + nb;
    const int rp0 = __builtin_amdgcn_readfirstlane(rowptr[min(n0w + 0, N_)]);
    const int rp1 = __builtin_amdgcn_readfirstlane(rowptr[min(n0w + 1, N_)]);
    const int rp2 = __builtin_amdgcn_readfirstlane(rowptr[min(n0w + 2, N_)]);
    const int rp3 = __builtin_amdgcn_readfirstlane(rowptr[min(n0w + 3, N_)]);
    const int rp4 = __builtin_amdgcn_readfirstlane(rowptr[min(n0w + 4, N_)]);
    const int base = rp0, cnt = rp4 - rp0;
    const int e1 = rp1 - rp0, e2 = rp2 - rp0, e3 = rp3 - rp0;
    const int* nbp = nbr + base;

    float a0 = 0.f, a1 = 0.f, a2 = 0.f, a3 = 0.f;

    if (K == 64) {
        const __hip_bfloat16* hbp = hin_b + lane;
        int idxb[16];
        #pragma unroll
        for (int u = 0; u < 16; ++u) idxb[u] = nbp[u];
        for (int k = 0; k < cnt; k += 16) {
            int nxt[16];
            #pragma unroll
            for (int u = 0; u < 16; ++u) nxt[u] = nbp[k + 16 + u];
            #pragma unroll
            for (int u = 0; u < 16; ++u) {
                float v = __bfloat162float(hbp[(size_t)idxb[u] * DD]);
                int j = k + u;
                a0 += (j < e1)             ? v : 0.f;
                a1 += (j >= e1 && j < e2)  ? v : 0.f;
                a2 += (j >= e2 && j < e3)  ? v : 0.f;
                a3 += (j >= e3 && j < cnt) ? v : 0.f;
            }
            #pragma unroll
            for (int u = 0; u < 16; ++u) idxb[u] = nxt[u];
        }
        if (n0w + 0 < N_) a0 += eps1 * hin[(size_t)(n0w + 0) * in_stride + lane];
        if (n0w + 1 < N_) a1 += eps1 * hin[(size_t)(n0w + 1) * in_stride + lane];
        if (n0w + 2 < N_) a2 += eps1 * hin[(size_t)(n0w + 2) * in_stride + lane];
        if (n0w + 3 < N_) a3 += eps1 * hin[(size_t)(n0w + 3) * in_stride + lane];
        float4 o = { a0, a1, a2, a3 };
        *(float4*)&s_hinT[lane][nb] = o;
    } else {
        // K == 32: fp32 rows; lanes 0-31 = even edges, 32-63 = odd edges
        const int d = lane & 31, rs = lane >> 5;
        const float* xp = hin + d;
        int idxb[8];
        #pragma unroll
        for (int u = 0; u < 8; ++u) idxb[u] = nbp[2 * u + rs];
        for (int k = 0; k < cnt; k += 16) {
            int nxt[8];
            #pragma unroll
            for (int u = 0; u < 8; ++u) nxt[u] = nbp[k + 16 + 2 * u + rs];
            #pragma unroll
            for (int u = 0; u < 8; ++u) {
                float v = xp[(size_t)idxb[u] * in_stride];
                int j = k + 2 * u + rs;
                a0 += (j < e1)             ? v : 0.f;
                a1 += (j >= e1 && j < e2)  ? v : 0.f;
                a2 += (j >= e2 && j < e3)  ? v : 0.f;
                a3 += (j >= e3 && j < cnt) ? v : 0.f;
            }
            #pragma unroll
            for (int u = 0; u < 8; ++u) idxb[u] = nxt[u];
        }
        a0 += __shfl_xor(a0, 32);
        a1 += __shfl_xor(a1, 32);
        a2 += __shfl_xor(a2, 32);
        a3 += __shfl_xor(a3, 32);
        if (rs == 0) {
            if (n0w + 0 < N_) a0 += eps1 * hin[(size_t)(n0w + 0) * in_stride + d];
            if (n0w + 1 < N_) a1 += eps1 * hin[(size_t)(n0w + 1) * in_stride + d];
            if (n0w + 2 < N_) a2 += eps1 * hin[(size_t)(n0w + 2) * in_stride + d];
            if (n0w + 3 < N_) a3 += eps1 * hin[(size_t)(n0w + 3) * in_stride + d];
            float4 o = { a0, a1, a2, a3 };
            *(float4*)&s_hinT[d][nb] = o;
        }
    }
    __syncthreads();

    // GEMV1: t1 = relu(hin @ W1 + b1) for 4 nodes per thread
    float r0 = b1[lane], r1 = r0, r2 = r0, r3 = r0;
    #pragma unroll 8
    for (int k = 0; k < K; ++k) {
        const float wv = s_W1[k * 64 + lane];
        const float4 h = *(const float4*)&s_hinT[k][nb];
        r0 += h.x * wv; r1 += h.y * wv; r2 += h.z * wv; r3 += h.w * wv;
    }
    {
        float4 o = { fmaxf(r0, 0.f), fmaxf(r1, 0.f), fmaxf(r2, 0.f), fmaxf(r3, 0.f) };
        *(float4*)&s_t1T[lane][nb] = o;   // same-wave producer/consumer: no barrier
    }

    // GEMV2 + BN
    float a0b = b2[lane], a1b = a0b, a2b = a0b, a3b = a0b;
    #pragma unroll 8
    for (int k = 0; k < 64; ++k) {
        const float wv = s_W2[k * 64 + lane];
        const float4 h = *(const float4*)&s_t1T[k][nb];
        a0b += h.x * wv; a1b += h.y * wv; a2b += h.z * wv; a3b += h.w * wv;
    }
    const float ga = gamma[lane], be = beta[lane], mu = mean[lane];
    const float iv = rsqrtf(var[lane] + 1e-5f);
    const int bb = node0 + nb;
    float o0 = ga * (fmaxf(a0b, 0.f) - mu) * iv + be;
    float o1 = ga * (fmaxf(a1b, 0.f) - mu) * iv + be;
    float o2 = ga * (fmaxf(a2b, 0.f) - mu) * iv + be;
    float o3 = ga * (fmaxf(a3b, 0.f) - mu) * iv + be;
    if (bb + 0 < N_) { out[(size_t)(bb + 0) * out_stride + lane] = o0; out_b[(size_t)(bb + 0) * DD + lane] = __float2bfloat16(o0); }
    if (bb + 1 < N_) { out[(size_t)(bb + 1) * out_stride + lane] = o1; out_b[(size_t)(bb + 1) * DD + lane] = __float2bfloat16(o1); }
    if (bb + 2 < N_) { out[(size_t)(bb + 2) * out_stride + lane] = o2; out_b[(size_t)(bb + 2) * DD + lane] = __float2bfloat16(o2); }
    if (bb + 3 < N_) { out[(size_t)(bb + 3) * out_stride + lane] = o3; out_b[(size_t)(bb + 3) * DD + lane] = __float2bfloat16(o3); }
}

// ---------------------------------------------------------------------------
// Mean-pool (batch sorted) — fp32 node_emb (keeps logits near-fp32)
// ---------------------------------------------------------------------------
__global__ void pool_kernel(const float* __restrict__ node_emb, const int* __restrict__ batch,
                            float* __restrict__ gsum, float* __restrict__ gcnt, int N_) {
    const int CHUNK = 256;
    __shared__ int sb[CHUNK];
    const int n0 = blockIdx.x * CHUNK;
    const int t  = threadIdx.x;
    const int cnt_local = min(n0 + CHUNK, N_) - n0;
    if (t < cnt_local) sb[t] = batch[n0 + t];
    __syncthreads();
    if (cnt_local <= 0) return;

    if (t < DD) {
        float acc = 0.0f;
        int curg = sb[0];
        for (int n = 0; n < cnt_local; ++n) {
            int g = sb[n];
            if (g != curg) {
                atomicAdd(&gsum[curg * DD + t], acc);
                acc = 0.0f; curg = g;
            }
            acc += node_emb[(long long)(n0 + n) * DD + t];
        }
        atomicAdd(&gsum[curg * DD + t], acc);
    } else if (t == DD) {
        int c = 1, curg = sb[0];
        for (int n = 1; n < cnt_local; ++n) {
            if (sb[n] != curg) {
                atomicAdd(&gcnt[curg], (float)c);
                c = 0; curg = sb[n];
            }
            ++c;
        }
        atomicAdd(&gcnt[curg], (float)c);
    }
}

// ---------------------------------------------------------------------------
// Classification head: one block per graph.
// ---------------------------------------------------------------------------
__global__ void head_kernel(const float* __restrict__ gsum, const float* __restrict__ gcnt,
                            const float* __restrict__ W1, const float* __restrict__ b1,
                            const float* __restrict__ W2, const float* __restrict__ b2,
                            const float* __restrict__ W3, const float* __restrict__ b3,
                            const float* __restrict__ W4, const float* __restrict__ b4,
                            float* __restrict__ class_out, int* __restrict__ comp_idx) {
    const int g = blockIdx.x;
    const int t = threadIdx.x;
    __shared__ float ge[DD], h1[128], h2[64], h3[64], logits[NCC];

    const float c = fmaxf(gcnt[g], 1.0f);
    if (t < DD) ge[t] = gsum[g * DD + t] / c;
    __syncthreads();

    if (t < 128) {
        float a = b1[t];
        #pragma unroll 4
        for (int k = 0; k < DD; ++k) a += ge[k] * W1[k * 128 + t];
        h1[t] = fmaxf(a, 0.0f);
    }
    __syncthreads();
    if (t < 64) {
        float a = b2[t];
        #pragma unroll 4
        for (int k = 0; k < 128; ++k) a += h1[k] * W2[k * 64 + t];
        h2[t] = fmaxf(a, 0.0f);
    }
    __syncthreads();
    if (t < 64) {
        float a = b3[t];
        #pragma unroll 4
        for (int k = 0; k < 64; ++k) a += h2[k] * W3[k * 64 + t];
        h3[t] = fmaxf(a, 0.0f);
    }
    __syncthreads();
    if (t < NCC) {
        float a = b4[t];
        #pragma unroll
        for (int k = 0; k < 64; ++k) a += h3[k] * W4[k * NCC + t];
        logits[t] = a;
    }
    __syncthreads();
    if (t == 0) {
        float mx = logits[0]; int am = 0;
        for (int j = 1; j < NCC; ++j) if (logits[j] > mx) { mx = logits[j]; am = j; }
        float se = 0.0f;
        for (int j = 0; j < NCC; ++j) se += expf(logits[j] - mx);
        float lse = logf(se);
        for (int j = 0; j < NCC; ++j) class_out[g * NCC + j] = logits[j] - mx - lse;
        comp_idx[g] = am;
    }
}

// ---------------------------------------------------------------------------
// prep_edge: pack ep_W1 (rows 192..383) and ep_W2 into MFMA B-fragment order;
// pc[10][128] = comp_emb @ W1a + b1.
// ---------------------------------------------------------------------------
__global__ void prep_edge(const float* __restrict__ W1, const float* __restrict__ b1,
                          const float* __restrict__ W2, const float* __restrict__ comp_emb,
                          unsigned short* __restrict__ W1b_p, unsigned short* __restrict__ W2_p,
                          float* __restrict__ pc) {
    int idx = blockIdx.x * 256 + threadIdx.x;
    const int S1 = 6 * 8 * 512;
    const int S2 = 4 * 4 * 512;
    if (idx < S1) {
        int frag = idx >> 9;
        int lane = (idx >> 3) & 63;
        int j = idx & 7;
        int kstep = frag >> 3, nt = frag & 7;
        int k = kstep * 32 + ((lane >> 4) << 3) + j;
        int n = nt * 16 + (lane & 15);
        W1b_p[idx] = f2bf_u(W1[(192 + k) * 128 + n]);
    } else if (idx < S1 + S2) {
        int i2 = idx - S1;
        int frag = i2 >> 9;
        int lane = (i2 >> 3) & 63;
        int j = i2 & 7;
        int kstep = frag >> 2, nt = frag & 3;
        int k = kstep * 32 + ((lane >> 4) << 3) + j;
        int n = nt * 16 + (lane & 15);
        W2_p[i2] = f2bf_u(W2[k * 64 + n]);
    } else if (idx < S1 + S2 + NCC * 128) {
        int i3 = idx - (S1 + S2);
        int ci = i3 >> 7, col = i3 & 127;
        float a = b1[col];
        for (int k = 0; k < DD; ++k) a += comp_emb[ci * DD + k] * W1[k * 128 + col];
        pc[i3] = a;
    }
}

// ---------------------------------------------------------------------------
// edge_mfma: 64 candidates per 256-thread block (4 waves). de rows gathered
// directly from bf16 hb (384B/row, no conversion).
// ---------------------------------------------------------------------------
__global__ __launch_bounds__(256) void edge_mfma(
    const int* __restrict__ cand, const int* __restrict__ batch,
    const int* __restrict__ comp_idx, const short* __restrict__ hb,
    const unsigned short* __restrict__ W1b_p, const unsigned short* __restrict__ W2_p,
    const float* __restrict__ pc, const float* __restrict__ W3,
    const float* __restrict__ b3, float* __restrict__ scores, int C_) {
    __shared__ char s_de[64 * 384];
    __shared__ char s_h1[64 * 256];
    __shared__ int s_node[64];
    __shared__ int s_ci[64];
    __shared__ float s_pc[NCC * 128];
    __shared__ float s_w3[64];

    const int t = threadIdx.x;
    const int lane = t & 63;
    const int w = t >> 6;
    const int c0 = blockIdx.x * 64;

    if (t < 64) {
        int c = c0 + t;
        int node = (c < C_) ? cand[c] : cand[0];
        s_node[t] = node;
        s_ci[t] = comp_idx[batch[node]];
        s_w3[t] = W3[t];
    }
    for (int i = t; i < NCC * 128; i += 256) s_pc[i] = pc[i];
    __syncthreads();

    // gather de rows (bf16) -> swizzled LDS; 24 x 16B chunks per row
    for (int i = t; i < 64 * 24; i += 256) {
        int r = i / 24, c8 = i - r * 24;
        bf16x8 v = *(const bf16x8*)(hb + (size_t)s_node[r] * DD + c8 * 8);
        int off = r * 384 + c8 * 16;
        *(bf16x8*)(s_de + (off ^ ((r & 7) << 4))) = v;
    }
    __syncthreads();

    f32x4 acc1[8];
    #pragma unroll
    for (int nt = 0; nt < 8; ++nt) acc1[nt] = (f32x4){0.f, 0.f, 0.f, 0.f};
    const int arow = w * 16 + (lane & 15);
    const int abase = arow * 384 + ((lane >> 4) << 4);
    #pragma unroll
    for (int ks = 0; ks < 6; ++ks) {
        bf16x8 a = *(const bf16x8*)(s_de + ((abase + ks * 64) ^ ((arow & 7) << 4)));
        #pragma unroll
        for (int nt = 0; nt < 8; ++nt) {
            bf16x8 b = *(const bf16x8*)(W1b_p + ((ks * 8 + nt) << 9) + (lane << 3));
            acc1[nt] = __builtin_amdgcn_mfma_f32_16x16x32_bf16(a, b, acc1[nt], 0, 0, 0);
        }
    }
    {
        const int rq = (lane >> 4) << 2;
        #pragma unroll
        for (int reg = 0; reg < 4; ++reg) {
            int row = w * 16 + rq + reg;
            int ci = s_ci[row];
            #pragma unroll
            for (int nt = 0; nt < 8; ++nt) {
                int col = nt * 16 + (lane & 15);
                float v = acc1[nt][reg] + s_pc[ci * 128 + col];
                v = fmaxf(v, 0.0f);
                int off = row * 256 + col * 2;
                *(unsigned short*)(s_h1 + (off ^ ((row & 7) << 4))) = f2bf_u(v);
            }
        }
    }
    __syncthreads();

    f32x4 acc2[4];
    #pragma unroll
    for (int nt = 0; nt < 4; ++nt) acc2[nt] = (f32x4){0.f, 0.f, 0.f, 0.f};
    const int a2base = arow * 256 + ((lane >> 4) << 4);
    #pragma unroll
    for (int ks = 0; ks < 4; ++ks) {
        bf16x8 a = *(const bf16x8*)(s_h1 + ((a2base + ks * 64) ^ ((arow & 7) << 4)));
        #pragma unroll
        for (int nt = 0; nt < 4; ++nt) {
            bf16x8 b = *(const bf16x8*)(W2_p + ((ks * 4 + nt) << 9) + (lane << 3));
            acc2[nt] = __builtin_amdgcn_mfma_f32_16x16x32_bf16(a, b, acc2[nt], 0, 0, 0);
        }
    }
    const float bb3 = b3[0];
    #pragma unroll
    for (int reg = 0; reg < 4; ++reg) {
        float p = 0.0f;
        #pragma unroll
        for (int nt = 0; nt < 4; ++nt)
            p += fmaxf(acc2[nt][reg], 0.0f) * s_w3[nt * 16 + (lane & 15)];
        p += __shfl_xor(p, 1);
        p += __shfl_xor(p, 2);
        p += __shfl_xor(p, 4);
        p += __shfl_xor(p, 8);
        if ((lane & 15) == 0) {
            int c = c0 + w * 16 + ((lane >> 4) << 2) + reg;
            if (c < C_) scores[c] = 1.0f / (1.0f + expf(-(p + bb3)));
        }
    }
}

// ---------------------------------------------------------------------------
extern "C" void kernel_launch(void* const* d_in, const int* in_sizes, int n_in,
                              void* d_out, int out_size, void* d_ws, size_t ws_size,
                              hipStream_t stream) {
    const float* x        = (const float*)d_in[0];
    const int*   ei       = (const int*)d_in[1];
    const int*   batch    = (const int*)d_in[2];
    const int*   cand     = (const int*)d_in[3];
    const float* c1_W1    = (const float*)d_in[4];
    const float* c1_b1    = (const float*)d_in[5];
    const float* c1_W2    = (const float*)d_in[6];
    const float* c1_b2    = (const float*)d_in[7];
    const float* c1_g     = (const float*)d_in[8];
    const float* c1_be    = (const float*)d_in[9];
    const float* c1_m     = (const float*)d_in[10];
    const float* c1_v     = (const float*)d_in[11];
    const float* c1_eps   = (const float*)d_in[12];
    const float* cs_W1    = (const float*)d_in[13];
    const float* cs_b1    = (const float*)d_in[14];
    const float* cs_W2    = (const float*)d_in[15];
    const float* cs_b2    = (const float*)d_in[16];
    const float* cs_g     = (const float*)d_in[17];
    const float* cs_be    = (const float*)d_in[18];
    const float* cs_m     = (const float*)d_in[19];
    const float* cs_v     = (const float*)d_in[20];
    const float* cs_eps   = (const float*)d_in[21];
    const float* nc_W1    = (const float*)d_in[22];
    const float* nc_b1    = (const float*)d_in[23];
    const float* nc_W2    = (const float*)d_in[24];
    const float* nc_b2    = (const float*)d_in[25];
    const float* nc_W3    = (const float*)d_in[26];
    const float* nc_b3    = (const float*)d_in[27];
    const float* nc_W4    = (const float*)d_in[28];
    const float* nc_b4    = (const float*)d_in[29];
    const float* comp_emb = (const float*)d_in[30];
    const float* ep_W1    = (const float*)d_in[31];
    const float* ep_b1    = (const float*)d_in[32];
    const float* ep_W2    = (const float*)d_in[33];
    const float* ep_b2    = (const float*)d_in[34];
    const float* ep_W3    = (const float*)d_in[35];
    const float* ep_b3    = (const float*)d_in[36];

    const int N_ = in_sizes[0] / 32;
    const int E_ = in_sizes[1] / 2;
    const int C_ = in_sizes[3];
    const int* src = ei;
    const int* dst = ei + E_;

    char* ws = (char*)d_ws;
    size_t off = 0;
    float* node_emb = (float*)(ws + off); off += (size_t)N_ * DD * 4;
    __hip_bfloat16* hb = (__hip_bfloat16*)(ws + off); off += (size_t)N_ * DD * 2;
    int*   rowptr   = (int*)(ws + off);   off += (size_t)(N_ + 2) * 4;
    int*   pos      = (int*)(ws + off);   off += (size_t)N_ * 4;
    int*   deg      = (int*)(ws + off);   off += (size_t)N_ * 4;
    int*   nbr      = (int*)(ws + off);   off += (size_t)(E_ + 64) * 4;
    int*   bsum     = (int*)(ws + off);   off += 4096;
    float* gsum     = (float*)(ws + off); off += (size_t)GG * DD * 4;
    float* gcnt     = (float*)(ws + off); off += 1024;
    int*   comp_idx = (int*)(ws + off);   off += 1024;
    float* pc       = (float*)(ws + off); off += NCC * 128 * 4;
    unsigned short* W1b_p = (unsigned short*)(ws + off); off += 6 * 8 * 512 * 2;
    unsigned short* W2_p  = (unsigned short*)(ws + off); off += 4 * 4 * 512 * 2;

    float* class_out = (float*)d_out;
    float* scores    = class_out + GG * NCC;

    // ---- edge weight prep (independent) ----
    prep_edge<<<(6 * 8 * 512 + 4 * 4 * 512 + NCC * 128 + 255) / 256, 256, 0, stream>>>(
        ep_W1, ep_b1, ep_W2, comp_emb, W1b_p, W2_p, pc);

    // ---- CSR build (once, reused by all 3 layers) ----
    hipMemsetAsync(deg, 0, (size_t)N_ * 4, stream);
    hipMemsetAsync(nbr + E_, 0, 64 * 4, stream);   // pad for chunked over-read
    deg_count<<<(E_ + 255) / 256, 256, 0, stream>>>(dst, deg, E_);
    const int nsb = (N_ + 1023) / 1024;
    scan1<<<nsb, 1024, 0, stream>>>(deg, rowptr, bsum, N_);
    scan2<<<1, 1024, 0, stream>>>(bsum, nsb);
    scan3<<<(N_ + 1 + 255) / 256, 256, 0, stream>>>(rowptr, pos, bsum, N_, E_);
    scatter_csr<<<(E_ + 255) / 256, 256, 0, stream>>>(src, dst, pos, nbr, E_);

    // ---- GIN layers (fused gather + MLP) ----
    const int gblk = (N_ + 31) / 32;
    gin_fused<32><<<gblk, 512, 0, stream>>>(
        x, 32, nullptr, rowptr, nbr, c1_W1, c1_b1, c1_W2, c1_b2,
        c1_g, c1_be, c1_m, c1_v, c1_eps, node_emb + 0, DD, hb + 0, N_);
    gin_fused<64><<<gblk, 512, 0, stream>>>(
        node_emb + 0, DD, hb + 0, rowptr, nbr,
        cs_W1 + 0 * 4096, cs_b1 + 0 * 64, cs_W2 + 0 * 4096, cs_b2 + 0 * 64,
        cs_g + 0 * 64, cs_be + 0 * 64, cs_m + 0 * 64, cs_v + 0 * 64, cs_eps + 0,
        node_emb + 64, DD, hb + 64, N_);
    gin_fused<64><<<gblk, 512, 0, stream>>>(
        node_emb + 64, DD, hb + 64, rowptr, nbr,
        cs_W1 + 1 * 4096, cs_b1 + 1 * 64, cs_W2 + 1 * 4096, cs_b2 + 1 * 64,
        cs_g + 1 * 64, cs_be + 1 * 64, cs_m + 1 * 64, cs_v + 1 * 64, cs_eps + 1,
        node_emb + 128, DD, hb + 128, N_);

    // ---- mean pool + head ----
    hipMemsetAsync(gsum, 0, (size_t)(GG * DD + GG) * 4, stream);
    pool_kernel<<<(N_ + 255) / 256, 256, 0, stream>>>(node_emb, batch, gsum, gcnt, N_);
    head_kernel<<<GG, 256, 0, stream>>>(gsum, gcnt, nc_W1, nc_b1, nc_W2, nc_b2,
                                        nc_W3, nc_b3, nc_W4, nc_b4, class_out, comp_idx);

    // ---- edge prediction (MFMA) ----
    edge_mfma<<<(C_ + 63) / 64, 256, 0, stream>>>(
        cand, batch, comp_idx, (const short*)hb, W1b_p, W2_p, pc, ep_W3, ep_b3, scores, C_);
}

// Round 6
// 447.451 us; speedup vs baseline: 3.8808x; 1.1635x over previous
//
#include <hip/hip_runtime.h>
#include <hip/hip_bf16.h>

// Problem constants (MultiTaskFEGIN): N=100000, E=1200000, F=32, H=64, L=3,
// G=256, C=200000, NC=10, D=L*H=192.

#define GG 256
#define NCC 10
#define DD 192
#define BSH 9          // bucket shift: 512 nodes/bucket (NB <= 256 for N <= 131072)

typedef short bf16x8 __attribute__((ext_vector_type(8)));
typedef float f32x4  __attribute__((ext_vector_type(4)));

__device__ inline unsigned short f2bf_u(float x) {
    __hip_bfloat16 h = __float2bfloat16(x);
    return *reinterpret_cast<unsigned short*>(&h);
}

// ---------------------------------------------------------------------------
// Binned CSR build: bucket by dst>>9 so all scatter writes land in contiguous
// per-bucket regions (full-line fills, no partial-sector writeback storm).
// ---------------------------------------------------------------------------
__global__ void bin_hist(const int* __restrict__ dst, int* __restrict__ bcnt, int E_) {
    __shared__ int h[256];
    h[threadIdx.x] = 0;
    __syncthreads();
    for (int e = blockIdx.x * 256 + threadIdx.x; e < E_; e += gridDim.x * 256)
        atomicAdd(&h[dst[e] >> BSH], 1);
    __syncthreads();
    if (h[threadIdx.x]) atomicAdd(&bcnt[threadIdx.x], h[threadIdx.x]);
}

__global__ void bin_scan(const int* __restrict__ bcnt, int* __restrict__ bbase,
                         int* __restrict__ bpos, int NB, int E_) {
    __shared__ int s[256];
    const int t = threadIdx.x;
    int v = (t < NB) ? bcnt[t] : 0;
    s[t] = v;
    __syncthreads();
    for (int off = 1; off < 256; off <<= 1) {
        int x = (t >= off) ? s[t - off] : 0;
        __syncthreads();
        s[t] += x;
        __syncthreads();
    }
    if (t < NB) { bbase[t] = s[t] - v; bpos[t] = s[t] - v; }
    if (t == 0) bbase[NB] = E_;
}

// 2048 edges/block: LDS rank per bucket + one global range-claim per bucket.
__global__ __launch_bounds__(256) void bin_scatter(
    const int* __restrict__ src, const int* __restrict__ dst,
    int* __restrict__ bpos, int2* __restrict__ ebuf, int E_) {
    __shared__ int h[256];
    __shared__ int base[256];
    const int t = threadIdx.x;
    const int e0 = blockIdx.x * 2048;
    h[t] = 0;
    __syncthreads();
    int myb[8], mys[8], myd[8], myr[8];
    #pragma unroll
    for (int u = 0; u < 8; ++u) {
        int e = e0 + t + u * 256;
        if (e < E_) {
            int d = dst[e];
            myb[u] = d >> BSH;
            myd[u] = d;
            mys[u] = src[e];
            myr[u] = atomicAdd(&h[myb[u]], 1);
        } else myb[u] = -1;
    }
    __syncthreads();
    if (h[t]) base[t] = atomicAdd(&bpos[t], h[t]);
    __syncthreads();
    #pragma unroll
    for (int u = 0; u < 8; ++u)
        if (myb[u] >= 0)
            ebuf[base[myb[u]] + myr[u]] = make_int2(mys[u], myd[u]);
}

// One block per bucket: local 512-bin histogram -> scan -> rowptr -> nbr.
__global__ __launch_bounds__(256) void csr_bucket(
    const int2* __restrict__ ebuf, const int* __restrict__ bbase,
    int* __restrict__ rowptr, int* __restrict__ nbr, int N_, int NB) {
    __shared__ int lh[512];
    __shared__ int lx[512];
    __shared__ int ps[256];
    const int b = blockIdx.x;
    const int t = threadIdx.x;
    const int ebase = bbase[b], eend = bbase[b + 1];
    const int ecnt = eend - ebase;
    const int n0 = b << BSH;

    for (int i = t; i < 512; i += 256) lh[i] = 0;
    __syncthreads();
    for (int i = t; i < ecnt; i += 256)
        atomicAdd(&lh[ebuf[ebase + i].y - n0], 1);
    __syncthreads();

    // exclusive scan of 512 via pair-scan with 256 threads
    int pv = lh[2 * t] + lh[2 * t + 1];
    ps[t] = pv;
    __syncthreads();
    for (int off = 1; off < 256; off <<= 1) {
        int x = (t >= off) ? ps[t - off] : 0;
        __syncthreads();
        ps[t] += x;
        __syncthreads();
    }
    const int excl = ps[t] - pv;
    lx[2 * t] = excl;
    lx[2 * t + 1] = excl + lh[2 * t];
    __syncthreads();

    for (int i = t; i < 512; i += 256) {
        int n = n0 + i;
        if (n < N_) rowptr[n] = ebase + lx[i];
    }
    if (b == NB - 1 && t == 0) rowptr[N_] = eend;

    // reuse lh as running positions
    for (int i = t; i < 512; i += 256) lh[i] = lx[i];
    __syncthreads();
    for (int i = t; i < ecnt; i += 256) {
        int2 p = ebuf[ebase + i];
        int r = atomicAdd(&lh[p.y - n0], 1);
        nbr[ebase + r] = p.x;
    }
}

// ---------------------------------------------------------------------------
// Fused GIN layer: combined-span chunked gather (deep ILP) + 2-layer MLP + BN.
// 32 nodes/block (512 thr, 8 waves, 4 consecutive nodes/wave). The wave's 4
// CSR spans are one contiguous range [rowptr[n], rowptr[n+4]): walk it in
// 16-edge chunks, all row loads independent, ownership via 3 uniform boundary
// compares. Index chunk prefetched one ahead (breaks idx->row chain).
// K=64: bf16 rows (128B aligned, 1 line). K=32: fp32 rows, 2 rows per load.
// nbr[] must be padded with >=64 zeroed ints past E.
// ---------------------------------------------------------------------------
template<int K>
__global__ __launch_bounds__(512) void gin_fused(
    const float* __restrict__ hin, int in_stride,
    const __hip_bfloat16* __restrict__ hin_b,      // slice ptr, stride DD (K=64)
    const int* __restrict__ rowptr, const int* __restrict__ nbr,
    const float* __restrict__ W1, const float* __restrict__ b1,
    const float* __restrict__ W2, const float* __restrict__ b2,
    const float* __restrict__ gamma, const float* __restrict__ beta,
    const float* __restrict__ mean, const float* __restrict__ var,
    const float* __restrict__ eps_p,
    float* __restrict__ out, int out_stride,
    __hip_bfloat16* __restrict__ out_b,            // slice ptr, stride DD
    int N_) {
    constexpr int NT = 32;
    constexpr int PAD = 36;
    __shared__ float s_hinT[K][PAD];
    __shared__ float s_t1T[64][PAD];
    __shared__ float s_W1[K * 64];
    __shared__ float s_W2[64 * 64];

    const int t = threadIdx.x;
    const int lane = t & 63;
    const int w = t >> 6;
    const int node0 = blockIdx.x * NT;
    const int nb = w * 4;

    // stage weights (float4)
    {
        const float4* W1v = (const float4*)W1;
        float4* s1 = (float4*)s_W1;
        for (int i = t; i < K * 16; i += 512) s1[i] = W1v[i];
        const float4* W2v = (const float4*)W2;
        float4* s2 = (float4*)s_W2;
        for (int i = t; i < 1024; i += 512) s2[i] = W2v[i];
    }

    const float eps1 = 1.0f + eps_p[0];

    // ---- combined-span gather for this wave's 4 nodes ----
    const int n0w = node0 + nb;
    const int rp0 = __builtin_amdgcn_readfirstlane(rowptr[min(n0w + 0, N_)]);
    const int rp1 = __builtin_amdgcn_readfirstlane(rowptr[min(n0w + 1, N_)]);
    const int rp2 = __builtin_amdgcn_readfirstlane(rowptr[min(n0w + 2, N_)]);
    const int rp3 = __builtin_amdgcn_readfirstlane(rowptr[min(n0w + 3, N_)]);
    const int rp4 = __builtin_amdgcn_readfirstlane(rowptr[min(n0w + 4, N_)]);
    const int base = rp0, cnt = rp4 - rp0;
    const int e1 = rp1 - rp0, e2 = rp2 - rp0, e3 = rp3 - rp0;
    const int* nbp = nbr + base;

    float a0 = 0.f, a1 = 0.f, a2 = 0.f, a3 = 0.f;

    if (K == 64) {
        const __hip_bfloat16* hbp = hin_b + lane;
        int idxb[16];
        #pragma unroll
        for (int u = 0; u < 16; ++u) idxb[u] = nbp[u];
        for (int k = 0; k < cnt; k += 16) {
            int nxt[16];
            #pragma unroll
            for (int u = 0; u < 16; ++u) nxt[u] = nbp[k + 16 + u];
            #pragma unroll
            for (int u = 0; u < 16; ++u) {
                float v = __bfloat162float(hbp[(size_t)idxb[u] * DD]);
                int j = k + u;
                a0 += (j < e1)             ? v : 0.f;
                a1 += (j >= e1 && j < e2)  ? v : 0.f;
                a2 += (j >= e2 && j < e3)  ? v : 0.f;
                a3 += (j >= e3 && j < cnt) ? v : 0.f;
            }
            #pragma unroll
            for (int u = 0; u < 16; ++u) idxb[u] = nxt[u];
        }
        if (n0w + 0 < N_) a0 += eps1 * hin[(size_t)(n0w + 0) * in_stride + lane];
        if (n0w + 1 < N_) a1 += eps1 * hin[(size_t)(n0w + 1) * in_stride + lane];
        if (n0w + 2 < N_) a2 += eps1 * hin[(size_t)(n0w + 2) * in_stride + lane];
        if (n0w + 3 < N_) a3 += eps1 * hin[(size_t)(n0w + 3) * in_stride + lane];
        float4 o = { a0, a1, a2, a3 };
        *(float4*)&s_hinT[lane][nb] = o;
    } else {
        // K == 32: fp32 rows; lanes 0-31 = even edges, 32-63 = odd edges
        const int d = lane & 31, rs = lane >> 5;
        const float* xp = hin + d;
        int idxb[8];
        #pragma unroll
        for (int u = 0; u < 8; ++u) idxb[u] = nbp[2 * u + rs];
        for (int k = 0; k < cnt; k += 16) {
            int nxt[8];
            #pragma unroll
            for (int u = 0; u < 8; ++u) nxt[u] = nbp[k + 16 + 2 * u + rs];
            #pragma unroll
            for (int u = 0; u < 8; ++u) {
                float v = xp[(size_t)idxb[u] * in_stride];
                int j = k + 2 * u + rs;
                a0 += (j < e1)             ? v : 0.f;
                a1 += (j >= e1 && j < e2)  ? v : 0.f;
                a2 += (j >= e2 && j < e3)  ? v : 0.f;
                a3 += (j >= e3 && j < cnt) ? v : 0.f;
            }
            #pragma unroll
            for (int u = 0; u < 8; ++u) idxb[u] = nxt[u];
        }
        a0 += __shfl_xor(a0, 32);
        a1 += __shfl_xor(a1, 32);
        a2 += __shfl_xor(a2, 32);
        a3 += __shfl_xor(a3, 32);
        if (rs == 0) {
            if (n0w + 0 < N_) a0 += eps1 * hin[(size_t)(n0w + 0) * in_stride + d];
            if (n0w + 1 < N_) a1 += eps1 * hin[(size_t)(n0w + 1) * in_stride + d];
            if (n0w + 2 < N_) a2 += eps1 * hin[(size_t)(n0w + 2) * in_stride + d];
            if (n0w + 3 < N_) a3 += eps1 * hin[(size_t)(n0w + 3) * in_stride + d];
            float4 o = { a0, a1, a2, a3 };
            *(float4*)&s_hinT[d][nb] = o;
        }
    }
    __syncthreads();

    // GEMV1: t1 = relu(hin @ W1 + b1) for 4 nodes per thread
    float r0 = b1[lane], r1 = r0, r2 = r0, r3 = r0;
    #pragma unroll 8
    for (int k = 0; k < K; ++k) {
        const float wv = s_W1[k * 64 + lane];
        const float4 h = *(const float4*)&s_hinT[k][nb];
        r0 += h.x * wv; r1 += h.y * wv; r2 += h.z * wv; r3 += h.w * wv;
    }
    {
        float4 o = { fmaxf(r0, 0.f), fmaxf(r1, 0.f), fmaxf(r2, 0.f), fmaxf(r3, 0.f) };
        *(float4*)&s_t1T[lane][nb] = o;   // same-wave producer/consumer: no barrier
    }

    // GEMV2 + BN
    float a0b = b2[lane], a1b = a0b, a2b = a0b, a3b = a0b;
    #pragma unroll 8
    for (int k = 0; k < 64; ++k) {
        const float wv = s_W2[k * 64 + lane];
        const float4 h = *(const float4*)&s_t1T[k][nb];
        a0b += h.x * wv; a1b += h.y * wv; a2b += h.z * wv; a3b += h.w * wv;
    }
    const float ga = gamma[lane], be = beta[lane], mu = mean[lane];
    const float iv = rsqrtf(var[lane] + 1e-5f);
    const int bb = node0 + nb;
    float o0 = ga * (fmaxf(a0b, 0.f) - mu) * iv + be;
    float o1 = ga * (fmaxf(a1b, 0.f) - mu) * iv + be;
    float o2 = ga * (fmaxf(a2b, 0.f) - mu) * iv + be;
    float o3 = ga * (fmaxf(a3b, 0.f) - mu) * iv + be;
    if (bb + 0 < N_) { out[(size_t)(bb + 0) * out_stride + lane] = o0; out_b[(size_t)(bb + 0) * DD + lane] = __float2bfloat16(o0); }
    if (bb + 1 < N_) { out[(size_t)(bb + 1) * out_stride + lane] = o1; out_b[(size_t)(bb + 1) * DD + lane] = __float2bfloat16(o1); }
    if (bb + 2 < N_) { out[(size_t)(bb + 2) * out_stride + lane] = o2; out_b[(size_t)(bb + 2) * DD + lane] = __float2bfloat16(o2); }
    if (bb + 3 < N_) { out[(size_t)(bb + 3) * out_stride + lane] = o3; out_b[(size_t)(bb + 3) * DD + lane] = __float2bfloat16(o3); }
}

// ---------------------------------------------------------------------------
// Mean-pool (batch sorted) — fp32 node_emb (keeps logits near-fp32)
// ---------------------------------------------------------------------------
__global__ void pool_kernel(const float* __restrict__ node_emb, const int* __restrict__ batch,
                            float* __restrict__ gsum, float* __restrict__ gcnt, int N_) {
    const int CHUNK = 256;
    __shared__ int sb[CHUNK];
    const int n0 = blockIdx.x * CHUNK;
    const int t  = threadIdx.x;
    const int cnt_local = min(n0 + CHUNK, N_) - n0;
    if (t < cnt_local) sb[t] = batch[n0 + t];
    __syncthreads();
    if (cnt_local <= 0) return;

    if (t < DD) {
        float acc = 0.0f;
        int curg = sb[0];
        for (int n = 0; n < cnt_local; ++n) {
            int g = sb[n];
            if (g != curg) {
                atomicAdd(&gsum[curg * DD + t], acc);
                acc = 0.0f; curg = g;
            }
            acc += node_emb[(long long)(n0 + n) * DD + t];
        }
        atomicAdd(&gsum[curg * DD + t], acc);
    } else if (t == DD) {
        int c = 1, curg = sb[0];
        for (int n = 1; n < cnt_local; ++n) {
            if (sb[n] != curg) {
                atomicAdd(&gcnt[curg], (float)c);
                c = 0; curg = sb[n];
            }
            ++c;
        }
        atomicAdd(&gcnt[curg], (float)c);
    }
}

// ---------------------------------------------------------------------------
// Classification head: one block per graph.
// ---------------------------------------------------------------------------
__global__ void head_kernel(const float* __restrict__ gsum, const float* __restrict__ gcnt,
                            const float* __restrict__ W1, const float* __restrict__ b1,
                            const float* __restrict__ W2, const float* __restrict__ b2,
                            const float* __restrict__ W3, const float* __restrict__ b3,
                            const float* __restrict__ W4, const float* __restrict__ b4,
                            float* __restrict__ class_out, int* __restrict__ comp_idx) {
    const int g = blockIdx.x;
    const int t = threadIdx.x;
    __shared__ float ge[DD], h1[128], h2[64], h3[64], logits[NCC];

    const float c = fmaxf(gcnt[g], 1.0f);
    if (t < DD) ge[t] = gsum[g * DD + t] / c;
    __syncthreads();

    if (t < 128) {
        float a = b1[t];
        #pragma unroll 4
        for (int k = 0; k < DD; ++k) a += ge[k] * W1[k * 128 + t];
        h1[t] = fmaxf(a, 0.0f);
    }
    __syncthreads();
    if (t < 64) {
        float a = b2[t];
        #pragma unroll 4
        for (int k = 0; k < 128; ++k) a += h1[k] * W2[k * 64 + t];
        h2[t] = fmaxf(a, 0.0f);
    }
    __syncthreads();
    if (t < 64) {
        float a = b3[t];
        #pragma unroll 4
        for (int k = 0; k < 64; ++k) a += h2[k] * W3[k * 64 + t];
        h3[t] = fmaxf(a, 0.0f);
    }
    __syncthreads();
    if (t < NCC) {
        float a = b4[t];
        #pragma unroll
        for (int k = 0; k < 64; ++k) a += h3[k] * W4[k * NCC + t];
        logits[t] = a;
    }
    __syncthreads();
    if (t == 0) {
        float mx = logits[0]; int am = 0;
        for (int j = 1; j < NCC; ++j) if (logits[j] > mx) { mx = logits[j]; am = j; }
        float se = 0.0f;
        for (int j = 0; j < NCC; ++j) se += expf(logits[j] - mx);
        float lse = logf(se);
        for (int j = 0; j < NCC; ++j) class_out[g * NCC + j] = logits[j] - mx - lse;
        comp_idx[g] = am;
    }
}

// ---------------------------------------------------------------------------
// prep_edge: pack ep_W1 (rows 192..383) and ep_W2 into MFMA B-fragment order;
// pc[10][128] = comp_emb @ W1a + b1.
// ---------------------------------------------------------------------------
__global__ void prep_edge(const float* __restrict__ W1, const float* __restrict__ b1,
                          const float* __restrict__ W2, const float* __restrict__ comp_emb,
                          unsigned short* __restrict__ W1b_p, unsigned short* __restrict__ W2_p,
                          float* __restrict__ pc) {
    int idx = blockIdx.x * 256 + threadIdx.x;
    const int S1 = 6 * 8 * 512;
    const int S2 = 4 * 4 * 512;
    if (idx < S1) {
        int frag = idx >> 9;
        int lane = (idx >> 3) & 63;
        int j = idx & 7;
        int kstep = frag >> 3, nt = frag & 7;
        int k = kstep * 32 + ((lane >> 4) << 3) + j;
        int n = nt * 16 + (lane & 15);
        W1b_p[idx] = f2bf_u(W1[(192 + k) * 128 + n]);
    } else if (idx < S1 + S2) {
        int i2 = idx - S1;
        int frag = i2 >> 9;
        int lane = (i2 >> 3) & 63;
        int j = i2 & 7;
        int kstep = frag >> 2, nt = frag & 3;
        int k = kstep * 32 + ((lane >> 4) << 3) + j;
        int n = nt * 16 + (lane & 15);
        W2_p[i2] = f2bf_u(W2[k * 64 + n]);
    } else if (idx < S1 + S2 + NCC * 128) {
        int i3 = idx - (S1 + S2);
        int ci = i3 >> 7, col = i3 & 127;
        float a = b1[col];
        for (int k = 0; k < DD; ++k) a += comp_emb[ci * DD + k] * W1[k * 128 + col];
        pc[i3] = a;
    }
}

// ---------------------------------------------------------------------------
// edge_mfma: 64 candidates per 256-thread block (4 waves). de rows gathered
// directly from bf16 hb (384B/row, no conversion).
// ---------------------------------------------------------------------------
__global__ __launch_bounds__(256) void edge_mfma(
    const int* __restrict__ cand, const int* __restrict__ batch,
    const int* __restrict__ comp_idx, const short* __restrict__ hb,
    const unsigned short* __restrict__ W1b_p, const unsigned short* __restrict__ W2_p,
    const float* __restrict__ pc, const float* __restrict__ W3,
    const float* __restrict__ b3, float* __restrict__ scores, int C_) {
    __shared__ char s_de[64 * 384];
    __shared__ char s_h1[64 * 256];
    __shared__ int s_node[64];
    __shared__ int s_ci[64];
    __shared__ float s_pc[NCC * 128];
    __shared__ float s_w3[64];

    const int t = threadIdx.x;
    const int lane = t & 63;
    const int w = t >> 6;
    const int c0 = blockIdx.x * 64;

    if (t < 64) {
        int c = c0 + t;
        int node = (c < C_) ? cand[c] : cand[0];
        s_node[t] = node;
        s_ci[t] = comp_idx[batch[node]];
        s_w3[t] = W3[t];
    }
    for (int i = t; i < NCC * 128; i += 256) s_pc[i] = pc[i];
    __syncthreads();

    // gather de rows (bf16) -> swizzled LDS; 24 x 16B chunks per row
    for (int i = t; i < 64 * 24; i += 256) {
        int r = i / 24, c8 = i - r * 24;
        bf16x8 v = *(const bf16x8*)(hb + (size_t)s_node[r] * DD + c8 * 8);
        int off = r * 384 + c8 * 16;
        *(bf16x8*)(s_de + (off ^ ((r & 7) << 4))) = v;
    }
    __syncthreads();

    f32x4 acc1[8];
    #pragma unroll
    for (int nt = 0; nt < 8; ++nt) acc1[nt] = (f32x4){0.f, 0.f, 0.f, 0.f};
    const int arow = w * 16 + (lane & 15);
    const int abase = arow * 384 + ((lane >> 4) << 4);
    #pragma unroll
    for (int ks = 0; ks < 6; ++ks) {
        bf16x8 a = *(const bf16x8*)(s_de + ((abase + ks * 64) ^ ((arow & 7) << 4)));
        #pragma unroll
        for (int nt = 0; nt < 8; ++nt) {
            bf16x8 b = *(const bf16x8*)(W1b_p + ((ks * 8 + nt) << 9) + (lane << 3));
            acc1[nt] = __builtin_amdgcn_mfma_f32_16x16x32_bf16(a, b, acc1[nt], 0, 0, 0);
        }
    }
    {
        const int rq = (lane >> 4) << 2;
        #pragma unroll
        for (int reg = 0; reg < 4; ++reg) {
            int row = w * 16 + rq + reg;
            int ci = s_ci[row];
            #pragma unroll
            for (int nt = 0; nt < 8; ++nt) {
                int col = nt * 16 + (lane & 15);
                float v = acc1[nt][reg] + s_pc[ci * 128 + col];
                v = fmaxf(v, 0.0f);
                int off = row * 256 + col * 2;
                *(unsigned short*)(s_h1 + (off ^ ((row & 7) << 4))) = f2bf_u(v);
            }
        }
    }
    __syncthreads();

    f32x4 acc2[4];
    #pragma unroll
    for (int nt = 0; nt < 4; ++nt) acc2[nt] = (f32x4){0.f, 0.f, 0.f, 0.f};
    const int a2base = arow * 256 + ((lane >> 4) << 4);
    #pragma unroll
    for (int ks = 0; ks < 4; ++ks) {
        bf16x8 a = *(const bf16x8*)(s_h1 + ((a2base + ks * 64) ^ ((arow & 7) << 4)));
        #pragma unroll
        for (int nt = 0; nt < 4; ++nt) {
            bf16x8 b = *(const bf16x8*)(W2_p + ((ks * 4 + nt) << 9) + (lane << 3));
            acc2[nt] = __builtin_amdgcn_mfma_f32_16x16x32_bf16(a, b, acc2[nt], 0, 0, 0);
        }
    }
    const float bb3 = b3[0];
    #pragma unroll
    for (int reg = 0; reg < 4; ++reg) {
        float p = 0.0f;
        #pragma unroll
        for (int nt = 0; nt < 4; ++nt)
            p += fmaxf(acc2[nt][reg], 0.0f) * s_w3[nt * 16 + (lane & 15)];
        p += __shfl_xor(p, 1);
        p += __shfl_xor(p, 2);
        p += __shfl_xor(p, 4);
        p += __shfl_xor(p, 8);
        if ((lane & 15) == 0) {
            int c = c0 + w * 16 + ((lane >> 4) << 2) + reg;
            if (c < C_) scores[c] = 1.0f / (1.0f + expf(-(p + bb3)));
        }
    }
}

// ---------------------------------------------------------------------------
extern "C" void kernel_launch(void* const* d_in, const int* in_sizes, int n_in,
                              void* d_out, int out_size, void* d_ws, size_t ws_size,
                              hipStream_t stream) {
    const float* x        = (const float*)d_in[0];
    const int*   ei       = (const int*)d_in[1];
    const int*   batch    = (const int*)d_in[2];
    const int*   cand     = (const int*)d_in[3];
    const float* c1_W1    = (const float*)d_in[4];
    const float* c1_b1    = (const float*)d_in[5];
    const float* c1_W2    = (const float*)d_in[6];
    const float* c1_b2    = (const float*)d_in[7];
    const float* c1_g     = (const float*)d_in[8];
    const float* c1_be    = (const float*)d_in[9];
    const float* c1_m     = (const float*)d_in[10];
    const float* c1_v     = (const float*)d_in[11];
    const float* c1_eps   = (const float*)d_in[12];
    const float* cs_W1    = (const float*)d_in[13];
    const float* cs_b1    = (const float*)d_in[14];
    const float* cs_W2    = (const float*)d_in[15];
    const float* cs_b2    = (const float*)d_in[16];
    const float* cs_g     = (const float*)d_in[17];
    const float* cs_be    = (const float*)d_in[18];
    const float* cs_m     = (const float*)d_in[19];
    const float* cs_v     = (const float*)d_in[20];
    const float* cs_eps   = (const float*)d_in[21];
    const float* nc_W1    = (const float*)d_in[22];
    const float* nc_b1    = (const float*)d_in[23];
    const float* nc_W2    = (const float*)d_in[24];
    const float* nc_b2    = (const float*)d_in[25];
    const float* nc_W3    = (const float*)d_in[26];
    const float* nc_b3    = (const float*)d_in[27];
    const float* nc_W4    = (const float*)d_in[28];
    const float* nc_b4    = (const float*)d_in[29];
    const float* comp_emb = (const float*)d_in[30];
    const float* ep_W1    = (const float*)d_in[31];
    const float* ep_b1    = (const float*)d_in[32];
    const float* ep_W2    = (const float*)d_in[33];
    const float* ep_b2    = (const float*)d_in[34];
    const float* ep_W3    = (const float*)d_in[35];
    const float* ep_b3    = (const float*)d_in[36];

    const int N_ = in_sizes[0] / 32;
    const int E_ = in_sizes[1] / 2;
    const int C_ = in_sizes[3];
    const int* src = ei;
    const int* dst = ei + E_;
    const int NB = (N_ + (1 << BSH) - 1) >> BSH;   // 196 buckets of 512 nodes

    char* ws = (char*)d_ws;
    size_t off = 0;
    float* node_emb = (float*)(ws + off); off += (size_t)N_ * DD * 4;
    __hip_bfloat16* hb = (__hip_bfloat16*)(ws + off); off += (size_t)N_ * DD * 2;
    int*   rowptr   = (int*)(ws + off);   off += (size_t)(N_ + 2) * 4;
    int*   nbr      = (int*)(ws + off);   off += (size_t)(E_ + 64) * 4;
    int*   bcnt     = (int*)(ws + off);   off += 1024;
    int*   bbase    = (int*)(ws + off);   off += 1044;   // NB+1 ints
    int*   bpos     = (int*)(ws + off);   off += 1024;
    float* gsum     = (float*)(ws + off); off += (size_t)GG * DD * 4;
    float* gcnt     = (float*)(ws + off); off += 1024;
    int*   comp_idx = (int*)(ws + off);   off += 1024;
    float* pc       = (float*)(ws + off); off += NCC * 128 * 4;
    unsigned short* W1b_p = (unsigned short*)(ws + off); off += 6 * 8 * 512 * 2;
    unsigned short* W2_p  = (unsigned short*)(ws + off); off += 4 * 4 * 512 * 2;
    // ebuf (E x int2 = 9.6MB) aliases node_emb: fully consumed by csr_bucket
    // before the first gin_fused writes node_emb (same stream, serial).
    int2*  ebuf     = (int2*)node_emb;

    float* class_out = (float*)d_out;
    float* scores    = class_out + GG * NCC;

    // ---- edge weight prep (independent) ----
    prep_edge<<<(6 * 8 * 512 + 4 * 4 * 512 + NCC * 128 + 255) / 256, 256, 0, stream>>>(
        ep_W1, ep_b1, ep_W2, comp_emb, W1b_p, W2_p, pc);

    // ---- binned CSR build ----
    hipMemsetAsync(bcnt, 0, 1024, stream);
    hipMemsetAsync(nbr + E_, 0, 64 * 4, stream);   // pad for chunked over-read
    bin_hist<<<1024, 256, 0, stream>>>(dst, bcnt, E_);
    bin_scan<<<1, 256, 0, stream>>>(bcnt, bbase, bpos, NB, E_);
    bin_scatter<<<(E_ + 2047) / 2048, 256, 0, stream>>>(src, dst, bpos, ebuf, E_);
    csr_bucket<<<NB, 256, 0, stream>>>(ebuf, bbase, rowptr, nbr, N_, NB);

    // ---- GIN layers (fused gather + MLP) ----
    const int gblk = (N_ + 31) / 32;
    gin_fused<32><<<gblk, 512, 0, stream>>>(
        x, 32, nullptr, rowptr, nbr, c1_W1, c1_b1, c1_W2, c1_b2,
        c1_g, c1_be, c1_m, c1_v, c1_eps, node_emb + 0, DD, hb + 0, N_);
    gin_fused<64><<<gblk, 512, 0, stream>>>(
        node_emb + 0, DD, hb + 0, rowptr, nbr,
        cs_W1 + 0 * 4096, cs_b1 + 0 * 64, cs_W2 + 0 * 4096, cs_b2 + 0 * 64,
        cs_g + 0 * 64, cs_be + 0 * 64, cs_m + 0 * 64, cs_v + 0 * 64, cs_eps + 0,
        node_emb + 64, DD, hb + 64, N_);
    gin_fused<64><<<gblk, 512, 0, stream>>>(
        node_emb + 64, DD, hb + 64, rowptr, nbr,
        cs_W1 + 1 * 4096, cs_b1 + 1 * 64, cs_W2 + 1 * 4096, cs_b2 + 1 * 64,
        cs_g + 1 * 64, cs_be + 1 * 64, cs_m + 1 * 64, cs_v + 1 * 64, cs_eps + 1,
        node_emb + 128, DD, hb + 128, N_);

    // ---- mean pool + head ----
    hipMemsetAsync(gsum, 0, (size_t)(GG * DD + GG) * 4, stream);
    pool_kernel<<<(N_ + 255) / 256, 256, 0, stream>>>(node_emb, batch, gsum, gcnt, N_);
    head_kernel<<<GG, 256, 0, stream>>>(gsum, gcnt, nc_W1, nc_b1, nc_W2, nc_b2,
                                        nc_W3, nc_b3, nc_W4, nc_b4, class_out, comp_idx);

    // ---- edge prediction (MFMA) ----
    edge_mfma<<<(C_ + 63) / 64, 256, 0, stream>>>(
        cand, batch, comp_idx, (const short*)hb, W1b_p, W2_p, pc, ep_W3, ep_b3, scores, C_);
}

// Round 7
// 362.890 us; speedup vs baseline: 4.7851x; 1.2330x over previous
//
#include <hip/hip_runtime.h>
#include <hip/hip_bf16.h>

// Problem constants (MultiTaskFEGIN): N=100000, E=1200000, F=32, H=64, L=3,
// G=256, C=200000, NC=10, D=L*H=192.

#define GG 256
#define NCC 10
#define DD 192
#define BSH 9          // bucket shift: 512 nodes/bucket (NB <= 256 for N <= 131072)

typedef short bf16x8 __attribute__((ext_vector_type(8)));
typedef float f32x4  __attribute__((ext_vector_type(4)));

__device__ inline unsigned short f2bf_u(float x) {
    __hip_bfloat16 h = __float2bfloat16(x);
    return *reinterpret_cast<unsigned short*>(&h);
}
__device__ inline float bf2f(unsigned short u) {
    return __uint_as_float(((unsigned int)u) << 16);
}

// ---------------------------------------------------------------------------
// Binned CSR build (R6, unchanged): contiguous per-bucket scatter regions.
// ---------------------------------------------------------------------------
__global__ void bin_hist(const int* __restrict__ dst, int* __restrict__ bcnt, int E_) {
    __shared__ int h[256];
    h[threadIdx.x] = 0;
    __syncthreads();
    for (int e = blockIdx.x * 256 + threadIdx.x; e < E_; e += gridDim.x * 256)
        atomicAdd(&h[dst[e] >> BSH], 1);
    __syncthreads();
    if (h[threadIdx.x]) atomicAdd(&bcnt[threadIdx.x], h[threadIdx.x]);
}

__global__ void bin_scan(const int* __restrict__ bcnt, int* __restrict__ bbase,
                         int* __restrict__ bpos, int NB, int E_) {
    __shared__ int s[256];
    const int t = threadIdx.x;
    int v = (t < NB) ? bcnt[t] : 0;
    s[t] = v;
    __syncthreads();
    for (int off = 1; off < 256; off <<= 1) {
        int x = (t >= off) ? s[t - off] : 0;
        __syncthreads();
        s[t] += x;
        __syncthreads();
    }
    if (t < NB) { bbase[t] = s[t] - v; bpos[t] = s[t] - v; }
    if (t == 0) bbase[NB] = E_;
}

__global__ __launch_bounds__(256) void bin_scatter(
    const int* __restrict__ src, const int* __restrict__ dst,
    int* __restrict__ bpos, int2* __restrict__ ebuf, int E_) {
    __shared__ int h[256];
    __shared__ int base[256];
    const int t = threadIdx.x;
    const int e0 = blockIdx.x * 2048;
    h[t] = 0;
    __syncthreads();
    int myb[8], mys[8], myd[8], myr[8];
    #pragma unroll
    for (int u = 0; u < 8; ++u) {
        int e = e0 + t + u * 256;
        if (e < E_) {
            int d = dst[e];
            myb[u] = d >> BSH;
            myd[u] = d;
            mys[u] = src[e];
            myr[u] = atomicAdd(&h[myb[u]], 1);
        } else myb[u] = -1;
    }
    __syncthreads();
    if (h[t]) base[t] = atomicAdd(&bpos[t], h[t]);
    __syncthreads();
    #pragma unroll
    for (int u = 0; u < 8; ++u)
        if (myb[u] >= 0)
            ebuf[base[myb[u]] + myr[u]] = make_int2(mys[u], myd[u]);
}

__global__ __launch_bounds__(256) void csr_bucket(
    const int2* __restrict__ ebuf, const int* __restrict__ bbase,
    int* __restrict__ rowptr, int* __restrict__ nbr, int N_, int NB) {
    __shared__ int lh[512];
    __shared__ int lx[512];
    __shared__ int ps[256];
    const int b = blockIdx.x;
    const int t = threadIdx.x;
    const int ebase = bbase[b], eend = bbase[b + 1];
    const int ecnt = eend - ebase;
    const int n0 = b << BSH;

    for (int i = t; i < 512; i += 256) lh[i] = 0;
    __syncthreads();
    for (int i = t; i < ecnt; i += 256)
        atomicAdd(&lh[ebuf[ebase + i].y - n0], 1);
    __syncthreads();

    int pv = lh[2 * t] + lh[2 * t + 1];
    ps[t] = pv;
    __syncthreads();
    for (int off = 1; off < 256; off <<= 1) {
        int x = (t >= off) ? ps[t - off] : 0;
        __syncthreads();
        ps[t] += x;
        __syncthreads();
    }
    const int excl = ps[t] - pv;
    lx[2 * t] = excl;
    lx[2 * t + 1] = excl + lh[2 * t];
    __syncthreads();

    for (int i = t; i < 512; i += 256) {
        int n = n0 + i;
        if (n < N_) rowptr[n] = ebase + lx[i];
    }
    if (b == NB - 1 && t == 0) rowptr[N_] = eend;

    for (int i = t; i < 512; i += 256) lh[i] = lx[i];
    __syncthreads();
    for (int i = t; i < ecnt; i += 256) {
        int2 p = ebuf[ebase + i];
        int r = atomicAdd(&lh[p.y - n0], 1);
        nbr[ebase + r] = p.x;
    }
}

// ---------------------------------------------------------------------------
// prep_enc: pack the 6 encoder weight matrices into MFMA B-fragment bf16.
// Regions (entries): c1_W1 K=32 -> 2048 @0; c1_W2 @2048; cs0_W1 @6144;
// cs0_W2 @10240; cs1_W1 @14336; cs1_W2 @18432. (each K=64 matrix = 4096)
// ---------------------------------------------------------------------------
__global__ void prep_enc(const float* __restrict__ c1W1, const float* __restrict__ c1W2,
                         const float* __restrict__ csW1, const float* __restrict__ csW2,
                         unsigned short* __restrict__ enc) {
    int idx = blockIdx.x * 256 + threadIdx.x;
    if (idx >= 22528) return;
    const float* W; int rel;
    if (idx < 2048)       { W = c1W1;        rel = idx; }
    else if (idx < 6144)  { W = c1W2;        rel = idx - 2048; }
    else if (idx < 10240) { W = csW1;        rel = idx - 6144; }
    else if (idx < 14336) { W = csW2;        rel = idx - 10240; }
    else if (idx < 18432) { W = csW1 + 4096; rel = idx - 14336; }
    else                  { W = csW2 + 4096; rel = idx - 18432; }
    int frag = rel >> 9;
    int lane = (rel >> 3) & 63;
    int j = rel & 7;
    int ks = frag >> 2, nt = frag & 3;
    int k = ks * 32 + ((lane >> 4) << 3) + j;
    int n = nt * 16 + (lane & 15);
    enc[idx] = f2bf_u(W[k * 64 + n]);
}

// ---------------------------------------------------------------------------
// Fused GIN layer: combined-span chunked gather (deep ILP) -> bf16 swizzled
// LDS -> MFMA 2-layer MLP -> BN -> bf16 hb slice. 32 nodes/block, 512 thr
// (8 waves: 4 nodes/wave gather; 1 16x16 C-tile/wave in each GEMM).
// LDS 12KB -> 4 blocks/CU. nbr[] padded >=64 ints past E.
// ---------------------------------------------------------------------------
#define SWZ(row, byte) ((byte) ^ (((row) & 7) << 4))

template<int K>
__global__ __launch_bounds__(512) void gin_fused(
    const float* __restrict__ x32,                 // K=32: fp32 input [N][32]
    const __hip_bfloat16* __restrict__ hin_b,      // K=64: bf16 slice, stride DD
    const int* __restrict__ rowptr, const int* __restrict__ nbr,
    const unsigned short* __restrict__ W1p, const float* __restrict__ b1,
    const unsigned short* __restrict__ W2p, const float* __restrict__ b2,
    const float* __restrict__ gamma, const float* __restrict__ beta,
    const float* __restrict__ mean, const float* __restrict__ var,
    const float* __restrict__ eps_p,
    __hip_bfloat16* __restrict__ out_b,            // slice ptr, stride DD
    int N_) {
    __shared__ char s_agg[32 * 128];   // bf16 [32 nodes][64 k], XOR-swizzled
    __shared__ char s_h1[32 * 128];
    __shared__ char s_out[32 * 128];

    const int t = threadIdx.x;
    const int lane = t & 63;
    const int w = t >> 6;
    const int node0 = blockIdx.x * 32;
    const int nb = w * 4;

    const float eps1 = 1.0f + eps_p[0];

    // ---- combined-span gather for this wave's 4 consecutive nodes ----
    const int n0w = node0 + nb;
    const int rp0 = __builtin_amdgcn_readfirstlane(rowptr[min(n0w + 0, N_)]);
    const int rp1 = __builtin_amdgcn_readfirstlane(rowptr[min(n0w + 1, N_)]);
    const int rp2 = __builtin_amdgcn_readfirstlane(rowptr[min(n0w + 2, N_)]);
    const int rp3 = __builtin_amdgcn_readfirstlane(rowptr[min(n0w + 3, N_)]);
    const int rp4 = __builtin_amdgcn_readfirstlane(rowptr[min(n0w + 4, N_)]);
    const int base = rp0, cnt = rp4 - rp0;
    const int e1 = rp1 - rp0, e2 = rp2 - rp0, e3 = rp3 - rp0;
    const int* nbp = nbr + base;

    float a0 = 0.f, a1 = 0.f, a2 = 0.f, a3 = 0.f;

    if (K == 64) {
        const __hip_bfloat16* hbp = hin_b + lane;
        int idxb[16];
        #pragma unroll
        for (int u = 0; u < 16; ++u) idxb[u] = nbp[u];
        for (int k = 0; k < cnt; k += 16) {
            int nxt[16];
            #pragma unroll
            for (int u = 0; u < 16; ++u) nxt[u] = nbp[k + 16 + u];
            #pragma unroll
            for (int u = 0; u < 16; ++u) {
                float v = __bfloat162float(hbp[(size_t)idxb[u] * DD]);
                int j = k + u;
                a0 += (j < e1)             ? v : 0.f;
                a1 += (j >= e1 && j < e2)  ? v : 0.f;
                a2 += (j >= e2 && j < e3)  ? v : 0.f;
                a3 += (j >= e3 && j < cnt) ? v : 0.f;
            }
            #pragma unroll
            for (int u = 0; u < 16; ++u) idxb[u] = nxt[u];
        }
        if (n0w + 0 < N_) a0 += eps1 * __bfloat162float(hbp[(size_t)(n0w + 0) * DD]);
        if (n0w + 1 < N_) a1 += eps1 * __bfloat162float(hbp[(size_t)(n0w + 1) * DD]);
        if (n0w + 2 < N_) a2 += eps1 * __bfloat162float(hbp[(size_t)(n0w + 2) * DD]);
        if (n0w + 3 < N_) a3 += eps1 * __bfloat162float(hbp[(size_t)(n0w + 3) * DD]);
        *(unsigned short*)(s_agg + SWZ(nb + 0, (nb + 0) * 128 + lane * 2)) = f2bf_u(a0);
        *(unsigned short*)(s_agg + SWZ(nb + 1, (nb + 1) * 128 + lane * 2)) = f2bf_u(a1);
        *(unsigned short*)(s_agg + SWZ(nb + 2, (nb + 2) * 128 + lane * 2)) = f2bf_u(a2);
        *(unsigned short*)(s_agg + SWZ(nb + 3, (nb + 3) * 128 + lane * 2)) = f2bf_u(a3);
    } else {
        // K == 32: fp32 rows; lanes 0-31 = even edges, 32-63 = odd edges
        const int d = lane & 31, rs = lane >> 5;
        const float* xp = x32 + d;
        int idxb[8];
        #pragma unroll
        for (int u = 0; u < 8; ++u) idxb[u] = nbp[2 * u + rs];
        for (int k = 0; k < cnt; k += 16) {
            int nxt[8];
            #pragma unroll
            for (int u = 0; u < 8; ++u) nxt[u] = nbp[k + 16 + 2 * u + rs];
            #pragma unroll
            for (int u = 0; u < 8; ++u) {
                float v = xp[(size_t)idxb[u] * 32];
                int j = k + 2 * u + rs;
                a0 += (j < e1)             ? v : 0.f;
                a1 += (j >= e1 && j < e2)  ? v : 0.f;
                a2 += (j >= e2 && j < e3)  ? v : 0.f;
                a3 += (j >= e3 && j < cnt) ? v : 0.f;
            }
            #pragma unroll
            for (int u = 0; u < 8; ++u) idxb[u] = nxt[u];
        }
        a0 += __shfl_xor(a0, 32);
        a1 += __shfl_xor(a1, 32);
        a2 += __shfl_xor(a2, 32);
        a3 += __shfl_xor(a3, 32);
        if (rs == 0) {
            if (n0w + 0 < N_) a0 += eps1 * xp[(size_t)(n0w + 0) * 32];
            if (n0w + 1 < N_) a1 += eps1 * xp[(size_t)(n0w + 1) * 32];
            if (n0w + 2 < N_) a2 += eps1 * xp[(size_t)(n0w + 2) * 32];
            if (n0w + 3 < N_) a3 += eps1 * xp[(size_t)(n0w + 3) * 32];
            *(unsigned short*)(s_agg + SWZ(nb + 0, (nb + 0) * 128 + d * 2)) = f2bf_u(a0);
            *(unsigned short*)(s_agg + SWZ(nb + 1, (nb + 1) * 128 + d * 2)) = f2bf_u(a1);
            *(unsigned short*)(s_agg + SWZ(nb + 2, (nb + 2) * 128 + d * 2)) = f2bf_u(a2);
            *(unsigned short*)(s_agg + SWZ(nb + 3, (nb + 3) * 128 + d * 2)) = f2bf_u(a3);
        }
    }
    __syncthreads();

    // ---- GEMM1: [32 x K] @ [K x 64] via MFMA; wave w -> C tile (mt, nt) ----
    const int mt = w >> 2, nt = w & 3;
    const int arow = mt * 16 + (lane & 15);
    const int col = nt * 16 + (lane & 15);
    f32x4 c1v = (f32x4){0.f, 0.f, 0.f, 0.f};
    #pragma unroll
    for (int ks = 0; ks < K / 32; ++ks) {
        bf16x8 a = *(const bf16x8*)(s_agg + SWZ(arow, arow * 128 + ks * 64 + ((lane >> 4) << 4)));
        bf16x8 b = *(const bf16x8*)(W1p + (((ks << 2) + nt) << 9) + (lane << 3));
        c1v = __builtin_amdgcn_mfma_f32_16x16x32_bf16(a, b, c1v, 0, 0, 0);
    }
    {
        const float bb1 = b1[col];
        #pragma unroll
        for (int reg = 0; reg < 4; ++reg) {
            int row = mt * 16 + ((lane >> 4) << 2) + reg;
            float v = fmaxf(c1v[reg] + bb1, 0.f);
            *(unsigned short*)(s_h1 + SWZ(row, row * 128 + col * 2)) = f2bf_u(v);
        }
    }
    __syncthreads();

    // ---- GEMM2: [32 x 64] @ [64 x 64] + BN epilogue ----
    f32x4 c2v = (f32x4){0.f, 0.f, 0.f, 0.f};
    #pragma unroll
    for (int ks = 0; ks < 2; ++ks) {
        bf16x8 a = *(const bf16x8*)(s_h1 + SWZ(arow, arow * 128 + ks * 64 + ((lane >> 4) << 4)));
        bf16x8 b = *(const bf16x8*)(W2p + (((ks << 2) + nt) << 9) + (lane << 3));
        c2v = __builtin_amdgcn_mfma_f32_16x16x32_bf16(a, b, c2v, 0, 0, 0);
    }
    {
        const float bb2 = b2[col];
        const float ga = gamma[col], bet = beta[col], mu = mean[col];
        const float iv = rsqrtf(var[col] + 1e-5f);
        #pragma unroll
        for (int reg = 0; reg < 4; ++reg) {
            int row = mt * 16 + ((lane >> 4) << 2) + reg;
            float v = fmaxf(c2v[reg] + bb2, 0.f);
            v = ga * (v - mu) * iv + bet;
            *(unsigned short*)(s_out + SWZ(row, row * 128 + col * 2)) = f2bf_u(v);
        }
    }
    __syncthreads();

    // ---- coalesced copy out: 32 rows x 128B, 16 threads/row x 8B ----
    {
        int r = t >> 4, c8 = t & 15;
        int node = node0 + r;
        if (node < N_) {
            ushort4 v = *(const ushort4*)(s_out + SWZ(r, r * 128 + c8 * 8));
            *(ushort4*)((unsigned short*)out_b + (size_t)node * DD + c8 * 4) = v;
        }
    }
}

// ---------------------------------------------------------------------------
// Mean-pool (batch sorted) — reads bf16 hb, fp32 accumulation
// ---------------------------------------------------------------------------
__global__ void pool_kernel(const unsigned short* __restrict__ hb, const int* __restrict__ batch,
                            float* __restrict__ gsum, float* __restrict__ gcnt, int N_) {
    const int CHUNK = 256;
    __shared__ int sb[CHUNK];
    const int n0 = blockIdx.x * CHUNK;
    const int t  = threadIdx.x;
    const int cnt_local = min(n0 + CHUNK, N_) - n0;
    if (t < cnt_local) sb[t] = batch[n0 + t];
    __syncthreads();
    if (cnt_local <= 0) return;

    if (t < DD) {
        float acc = 0.0f;
        int curg = sb[0];
        for (int n = 0; n < cnt_local; ++n) {
            int g = sb[n];
            if (g != curg) {
                atomicAdd(&gsum[curg * DD + t], acc);
                acc = 0.0f; curg = g;
            }
            acc += bf2f(hb[(size_t)(n0 + n) * DD + t]);
        }
        atomicAdd(&gsum[curg * DD + t], acc);
    } else if (t == DD) {
        int c = 1, curg = sb[0];
        for (int n = 1; n < cnt_local; ++n) {
            if (sb[n] != curg) {
                atomicAdd(&gcnt[curg], (float)c);
                c = 0; curg = sb[n];
            }
            ++c;
        }
        atomicAdd(&gcnt[curg], (float)c);
    }
}

// ---------------------------------------------------------------------------
// Classification head: one block per graph (fp32 throughout).
// ---------------------------------------------------------------------------
__global__ void head_kernel(const float* __restrict__ gsum, const float* __restrict__ gcnt,
                            const float* __restrict__ W1, const float* __restrict__ b1,
                            const float* __restrict__ W2, const float* __restrict__ b2,
                            const float* __restrict__ W3, const float* __restrict__ b3,
                            const float* __restrict__ W4, const float* __restrict__ b4,
                            float* __restrict__ class_out, int* __restrict__ comp_idx) {
    const int g = blockIdx.x;
    const int t = threadIdx.x;
    __shared__ float ge[DD], h1[128], h2[64], h3[64], logits[NCC];

    const float c = fmaxf(gcnt[g], 1.0f);
    if (t < DD) ge[t] = gsum[g * DD + t] / c;
    __syncthreads();

    if (t < 128) {
        float a = b1[t];
        #pragma unroll 4
        for (int k = 0; k < DD; ++k) a += ge[k] * W1[k * 128 + t];
        h1[t] = fmaxf(a, 0.0f);
    }
    __syncthreads();
    if (t < 64) {
        float a = b2[t];
        #pragma unroll 4
        for (int k = 0; k < 128; ++k) a += h1[k] * W2[k * 64 + t];
        h2[t] = fmaxf(a, 0.0f);
    }
    __syncthreads();
    if (t < 64) {
        float a = b3[t];
        #pragma unroll 4
        for (int k = 0; k < 64; ++k) a += h2[k] * W3[k * 64 + t];
        h3[t] = fmaxf(a, 0.0f);
    }
    __syncthreads();
    if (t < NCC) {
        float a = b4[t];
        #pragma unroll
        for (int k = 0; k < 64; ++k) a += h3[k] * W4[k * NCC + t];
        logits[t] = a;
    }
    __syncthreads();
    if (t == 0) {
        float mx = logits[0]; int am = 0;
        for (int j = 1; j < NCC; ++j) if (logits[j] > mx) { mx = logits[j]; am = j; }
        float se = 0.0f;
        for (int j = 0; j < NCC; ++j) se += expf(logits[j] - mx);
        float lse = logf(se);
        for (int j = 0; j < NCC; ++j) class_out[g * NCC + j] = logits[j] - mx - lse;
        comp_idx[g] = am;
    }
}

// ---------------------------------------------------------------------------
// prep_edge: pack ep_W1 (rows 192..383) and ep_W2 into MFMA B-fragment order;
// pc[10][128] = comp_emb @ W1a + b1.
// ---------------------------------------------------------------------------
__global__ void prep_edge(const float* __restrict__ W1, const float* __restrict__ b1,
                          const float* __restrict__ W2, const float* __restrict__ comp_emb,
                          unsigned short* __restrict__ W1b_p, unsigned short* __restrict__ W2_p,
                          float* __restrict__ pc) {
    int idx = blockIdx.x * 256 + threadIdx.x;
    const int S1 = 6 * 8 * 512;
    const int S2 = 4 * 4 * 512;
    if (idx < S1) {
        int frag = idx >> 9;
        int lane = (idx >> 3) & 63;
        int j = idx & 7;
        int kstep = frag >> 3, nt = frag & 7;
        int k = kstep * 32 + ((lane >> 4) << 3) + j;
        int n = nt * 16 + (lane & 15);
        W1b_p[idx] = f2bf_u(W1[(192 + k) * 128 + n]);
    } else if (idx < S1 + S2) {
        int i2 = idx - S1;
        int frag = i2 >> 9;
        int lane = (i2 >> 3) & 63;
        int j = i2 & 7;
        int kstep = frag >> 2, nt = frag & 3;
        int k = kstep * 32 + ((lane >> 4) << 3) + j;
        int n = nt * 16 + (lane & 15);
        W2_p[i2] = f2bf_u(W2[k * 64 + n]);
    } else if (idx < S1 + S2 + NCC * 128) {
        int i3 = idx - (S1 + S2);
        int ci = i3 >> 7, col = i3 & 127;
        float a = b1[col];
        for (int k = 0; k < DD; ++k) a += comp_emb[ci * DD + k] * W1[k * 128 + col];
        pc[i3] = a;
    }
}

// ---------------------------------------------------------------------------
// edge_mfma: 64 candidates per 256-thread block (4 waves). de rows gathered
// directly from bf16 hb (384B/row).
// ---------------------------------------------------------------------------
__global__ __launch_bounds__(256) void edge_mfma(
    const int* __restrict__ cand, const int* __restrict__ batch,
    const int* __restrict__ comp_idx, const short* __restrict__ hb,
    const unsigned short* __restrict__ W1b_p, const unsigned short* __restrict__ W2_p,
    const float* __restrict__ pc, const float* __restrict__ W3,
    const float* __restrict__ b3, float* __restrict__ scores, int C_) {
    __shared__ char s_de[64 * 384];
    __shared__ char s_h1[64 * 256];
    __shared__ int s_node[64];
    __shared__ int s_ci[64];
    __shared__ float s_pc[NCC * 128];
    __shared__ float s_w3[64];

    const int t = threadIdx.x;
    const int lane = t & 63;
    const int w = t >> 6;
    const int c0 = blockIdx.x * 64;

    if (t < 64) {
        int c = c0 + t;
        int node = (c < C_) ? cand[c] : cand[0];
        s_node[t] = node;
        s_ci[t] = comp_idx[batch[node]];
        s_w3[t] = W3[t];
    }
    for (int i = t; i < NCC * 128; i += 256) s_pc[i] = pc[i];
    __syncthreads();

    for (int i = t; i < 64 * 24; i += 256) {
        int r = i / 24, c8 = i - r * 24;
        bf16x8 v = *(const bf16x8*)(hb + (size_t)s_node[r] * DD + c8 * 8);
        int off = r * 384 + c8 * 16;
        *(bf16x8*)(s_de + (off ^ ((r & 7) << 4))) = v;
    }
    __syncthreads();

    f32x4 acc1[8];
    #pragma unroll
    for (int nt = 0; nt < 8; ++nt) acc1[nt] = (f32x4){0.f, 0.f, 0.f, 0.f};
    const int arow = w * 16 + (lane & 15);
    const int abase = arow * 384 + ((lane >> 4) << 4);
    #pragma unroll
    for (int ks = 0; ks < 6; ++ks) {
        bf16x8 a = *(const bf16x8*)(s_de + ((abase + ks * 64) ^ ((arow & 7) << 4)));
        #pragma unroll
        for (int nt = 0; nt < 8; ++nt) {
            bf16x8 b = *(const bf16x8*)(W1b_p + ((ks * 8 + nt) << 9) + (lane << 3));
            acc1[nt] = __builtin_amdgcn_mfma_f32_16x16x32_bf16(a, b, acc1[nt], 0, 0, 0);
        }
    }
    {
        const int rq = (lane >> 4) << 2;
        #pragma unroll
        for (int reg = 0; reg < 4; ++reg) {
            int row = w * 16 + rq + reg;
            int ci = s_ci[row];
            #pragma unroll
            for (int nt = 0; nt < 8; ++nt) {
                int col = nt * 16 + (lane & 15);
                float v = acc1[nt][reg] + s_pc[ci * 128 + col];
                v = fmaxf(v, 0.0f);
                int off = row * 256 + col * 2;
                *(unsigned short*)(s_h1 + (off ^ ((row & 7) << 4))) = f2bf_u(v);
            }
        }
    }
    __syncthreads();

    f32x4 acc2[4];
    #pragma unroll
    for (int nt = 0; nt < 4; ++nt) acc2[nt] = (f32x4){0.f, 0.f, 0.f, 0.f};
    const int a2base = arow * 256 + ((lane >> 4) << 4);
    #pragma unroll
    for (int ks = 0; ks < 4; ++ks) {
        bf16x8 a = *(const bf16x8*)(s_h1 + ((a2base + ks * 64) ^ ((arow & 7) << 4)));
        #pragma unroll
        for (int nt = 0; nt < 4; ++nt) {
            bf16x8 b = *(const bf16x8*)(W2_p + ((ks * 4 + nt) << 9) + (lane << 3));
            acc2[nt] = __builtin_amdgcn_mfma_f32_16x16x32_bf16(a, b, acc2[nt], 0, 0, 0);
        }
    }
    const float bb3 = b3[0];
    #pragma unroll
    for (int reg = 0; reg < 4; ++reg) {
        float p = 0.0f;
        #pragma unroll
        for (int nt = 0; nt < 4; ++nt)
            p += fmaxf(acc2[nt][reg], 0.0f) * s_w3[nt * 16 + (lane & 15)];
        p += __shfl_xor(p, 1);
        p += __shfl_xor(p, 2);
        p += __shfl_xor(p, 4);
        p += __shfl_xor(p, 8);
        if ((lane & 15) == 0) {
            int c = c0 + w * 16 + ((lane >> 4) << 2) + reg;
            if (c < C_) scores[c] = 1.0f / (1.0f + expf(-(p + bb3)));
        }
    }
}

// ---------------------------------------------------------------------------
extern "C" void kernel_launch(void* const* d_in, const int* in_sizes, int n_in,
                              void* d_out, int out_size, void* d_ws, size_t ws_size,
                              hipStream_t stream) {
    const float* x        = (const float*)d_in[0];
    const int*   ei       = (const int*)d_in[1];
    const int*   batch    = (const int*)d_in[2];
    const int*   cand     = (const int*)d_in[3];
    const float* c1_W1    = (const float*)d_in[4];
    const float* c1_b1    = (const float*)d_in[5];
    const float* c1_W2    = (const float*)d_in[6];
    const float* c1_b2    = (const float*)d_in[7];
    const float* c1_g     = (const float*)d_in[8];
    const float* c1_be    = (const float*)d_in[9];
    const float* c1_m     = (const float*)d_in[10];
    const float* c1_v     = (const float*)d_in[11];
    const float* c1_eps   = (const float*)d_in[12];
    const float* cs_W1    = (const float*)d_in[13];
    const float* cs_b1    = (const float*)d_in[14];
    const float* cs_W2    = (const float*)d_in[15];
    const float* cs_b2    = (const float*)d_in[16];
    const float* cs_g     = (const float*)d_in[17];
    const float* cs_be    = (const float*)d_in[18];
    const float* cs_m     = (const float*)d_in[19];
    const float* cs_v     = (const float*)d_in[20];
    const float* cs_eps   = (const float*)d_in[21];
    const float* nc_W1    = (const float*)d_in[22];
    const float* nc_b1    = (const float*)d_in[23];
    const float* nc_W2    = (const float*)d_in[24];
    const float* nc_b2    = (const float*)d_in[25];
    const float* nc_W3    = (const float*)d_in[26];
    const float* nc_b3    = (const float*)d_in[27];
    const float* nc_W4    = (const float*)d_in[28];
    const float* nc_b4    = (const float*)d_in[29];
    const float* comp_emb = (const float*)d_in[30];
    const float* ep_W1    = (const float*)d_in[31];
    const float* ep_b1    = (const float*)d_in[32];
    const float* ep_W2    = (const float*)d_in[33];
    const float* ep_b2    = (const float*)d_in[34];
    const float* ep_W3    = (const float*)d_in[35];
    const float* ep_b3    = (const float*)d_in[36];

    const int N_ = in_sizes[0] / 32;
    const int E_ = in_sizes[1] / 2;
    const int C_ = in_sizes[3];
    const int* src = ei;
    const int* dst = ei + E_;
    const int NB = (N_ + (1 << BSH) - 1) >> BSH;

    char* ws = (char*)d_ws;
    size_t off = 0;
    __hip_bfloat16* hb = (__hip_bfloat16*)(ws + off); off += (size_t)N_ * DD * 2;
    int*   rowptr   = (int*)(ws + off);   off += (size_t)(N_ + 2) * 4;
    int*   nbr      = (int*)(ws + off);   off += (size_t)(E_ + 64) * 4;
    int*   bcnt     = (int*)(ws + off);   off += 1024;
    int*   bbase    = (int*)(ws + off);   off += 1044;
    int*   bpos     = (int*)(ws + off);   off += 1024;
    float* gsum     = (float*)(ws + off); off += (size_t)GG * DD * 4;
    float* gcnt     = (float*)(ws + off); off += 1024;
    int*   comp_idx = (int*)(ws + off);   off += 1024;
    float* pc       = (float*)(ws + off); off += NCC * 128 * 4;
    unsigned short* W1b_p = (unsigned short*)(ws + off); off += 6 * 8 * 512 * 2;
    unsigned short* W2_p  = (unsigned short*)(ws + off); off += 4 * 4 * 512 * 2;
    unsigned short* enc   = (unsigned short*)(ws + off); off += 22528 * 2;
    // ebuf (E x int2 = 9.6MB) aliases hb: fully consumed by csr_bucket before
    // the first gin_fused writes hb (same stream, serial).
    int2*  ebuf     = (int2*)hb;

    float* class_out = (float*)d_out;
    float* scores    = class_out + GG * NCC;

    // ---- weight prep (independent of graph pipeline) ----
    prep_edge<<<(6 * 8 * 512 + 4 * 4 * 512 + NCC * 128 + 255) / 256, 256, 0, stream>>>(
        ep_W1, ep_b1, ep_W2, comp_emb, W1b_p, W2_p, pc);
    prep_enc<<<(22528 + 255) / 256, 256, 0, stream>>>(c1_W1, c1_W2, cs_W1, cs_W2, enc);

    // ---- binned CSR build ----
    hipMemsetAsync(bcnt, 0, 1024, stream);
    hipMemsetAsync(nbr + E_, 0, 64 * 4, stream);
    bin_hist<<<1024, 256, 0, stream>>>(dst, bcnt, E_);
    bin_scan<<<1, 256, 0, stream>>>(bcnt, bbase, bpos, NB, E_);
    bin_scatter<<<(E_ + 2047) / 2048, 256, 0, stream>>>(src, dst, bpos, ebuf, E_);
    csr_bucket<<<NB, 256, 0, stream>>>(ebuf, bbase, rowptr, nbr, N_, NB);

    // ---- GIN layers (fused gather + MFMA MLP) ----
    const int gblk = (N_ + 31) / 32;
    gin_fused<32><<<gblk, 512, 0, stream>>>(
        x, nullptr, rowptr, nbr,
        enc + 0, c1_b1, enc + 2048, c1_b2,
        c1_g, c1_be, c1_m, c1_v, c1_eps, hb + 0, N_);
    gin_fused<64><<<gblk, 512, 0, stream>>>(
        nullptr, hb + 0, rowptr, nbr,
        enc + 6144, cs_b1 + 0, enc + 10240, cs_b2 + 0,
        cs_g + 0, cs_be + 0, cs_m + 0, cs_v + 0, cs_eps + 0, hb + 64, N_);
    gin_fused<64><<<gblk, 512, 0, stream>>>(
        nullptr, hb + 64, rowptr, nbr,
        enc + 14336, cs_b1 + 64, enc + 18432, cs_b2 + 64,
        cs_g + 64, cs_be + 64, cs_m + 64, cs_v + 64, cs_eps + 1, hb + 128, N_);

    // ---- mean pool + head ----
    hipMemsetAsync(gsum, 0, (size_t)(GG * DD + GG) * 4, stream);
    pool_kernel<<<(N_ + 255) / 256, 256, 0, stream>>>((const unsigned short*)hb, batch, gsum, gcnt, N_);
    head_kernel<<<GG, 256, 0, stream>>>(gsum, gcnt, nc_W1, nc_b1, nc_W2, nc_b2,
                                        nc_W3, nc_b3, nc_W4, nc_b4, class_out, comp_idx);

    // ---- edge prediction (MFMA) ----
    edge_mfma<<<(C_ + 63) / 64, 256, 0, stream>>>(
        cand, batch, comp_idx, (const short*)hb, W1b_p, W2_p, pc, ep_W3, ep_b3, scores, C_);
}